// Round 3
// baseline (453.906 us; speedup 1.0000x reference)
//
#include <hip/hip_runtime.h>
#include <hip/hip_bf16.h>

#define HH 8
#define SS 128
#define CC 256
#define DD 32
#define NTOK 32768
#define NHB 2048
#define BNEPS 1e-5f

using bf16 = __hip_bfloat16;
typedef float f32x4 __attribute__((ext_vector_type(4)));
typedef __bf16 bf16x8 __attribute__((ext_vector_type(8)));

__device__ __forceinline__ bf16x8 ld8(const bf16* p) {
    return *reinterpret_cast<const bf16x8*>(p);
}
__device__ __forceinline__ f32x4 ldf4(const float* p) {
    return *reinterpret_cast<const f32x4*>(p);
}
__device__ __forceinline__ void st8(bf16* p, bf16x8 v) {
    *reinterpret_cast<bf16x8*>(p) = v;
}
// bit-pun __bf16 -> __hip_bfloat16 (avoids ambiguous operator=)
__device__ __forceinline__ bf16 bfc(__bf16 x) {
    union { __bf16 i; bf16 o; } u;
    u.i = x;
    return u.o;
}
// XOR swizzle: 16B-group index g within a 256B row, spread by row low bits.
// Returns element offset of the group start (8 elems = 16B per group).
__device__ __forceinline__ int swzg(int row, int g) {
    return ((g & 8) | ((g & 7) ^ (row & 7))) << 3;
}

// async global->LDS, 16B per lane. LDS dest must be wave-uniform base; lane l
// writes base + l*16 (m104 semantics). Global source is per-lane.
typedef __attribute__((address_space(1))) const void g_void;
typedef __attribute__((address_space(3))) void l_void;
__device__ __forceinline__ void gload_lds16(const bf16* g, bf16* l) {
    __builtin_amdgcn_global_load_lds((g_void*)g, (l_void*)l, 16, 0, 0);
}

// ---------------- prep: fp32->bf16 weight cvt (blocks 0..511) ∥ statsA(x) (blocks 512..639) ----------------
__global__ __launch_bounds__(256) void prep(const float* __restrict__ wq,
                                            const float* __restrict__ wk,
                                            const float* __restrict__ wv,
                                            const float* __restrict__ wo,
                                            const float* __restrict__ w0,
                                            const float* __restrict__ w1,
                                            bf16* __restrict__ out,
                                            const float* __restrict__ X,
                                            float* __restrict__ part) {
    int tid = threadIdx.x;
    if (blockIdx.x < 512) {
        int i = (blockIdx.x * 256 + tid) * 4;  // 0..524284
        const float* src;
        int off;
        if (i < 65536) { src = wq; off = i; }
        else if (i < 131072) { src = wk; off = i - 65536; }
        else if (i < 196608) { src = wv; off = i - 131072; }
        else if (i < 262144) { src = wo; off = i - 196608; }
        else if (i < 393216) { src = w0; off = i - 262144; }
        else { src = w1; off = i - 393216; }
        f32x4 v = ldf4(src + off);
#pragma unroll
        for (int u = 0; u < 4; u++) out[i + u] = __float2bfloat16(v[u]);
        return;
    }
    // statsA for x: CH=256 fp32, P=128 blocks, RB=256 rows, SLOTS=4, ITER=64
    int bx = blockIdx.x - 512;
    int cv = tid & 63, slot = tid >> 6;
    int c0 = cv * 4;
    size_t row0 = (size_t)bx * 256 + slot;
    float s[4], s2[4];
#pragma unroll
    for (int u = 0; u < 4; u++) { s[u] = 0.f; s2[u] = 0.f; }
    for (int i = 0; i < 64; i++) {
        size_t row = row0 + (size_t)i * 4;
        f32x4 v = ldf4(X + row * 256 + c0);
#pragma unroll
        for (int u = 0; u < 4; u++) {
            float f = v[u];
            s[u] += f; s2[u] += f * f;
        }
    }
    __shared__ float red[256][8];
#pragma unroll
    for (int u = 0; u < 4; u++) {
        red[tid][u] = s[u];
        red[tid][4 + u] = s2[u];
    }
    __syncthreads();
    if (tid < 64) {
#pragma unroll
        for (int sl = 1; sl < 4; sl++)
#pragma unroll
            for (int u = 0; u < 4; u++) {
                s[u] += red[tid + sl * 64][u];
                s2[u] += red[tid + sl * 64][4 + u];
            }
        float* dst = part + (size_t)bx * 512;
#pragma unroll
        for (int u = 0; u < 4; u++) {
            dst[c0 + u] = s[u];
            dst[256 + c0 + u] = s2[u];
        }
    }
}

// ---------------- stats stage A (wide CH, bf16): disjoint channels, NO atomics ----------------
template <int CH, int P, int ROWS>
__global__ __launch_bounds__(256) void statsA_wide(const bf16* __restrict__ X,
                                                   float* __restrict__ part) {
    constexpr int RB = ROWS / P;
    int c0 = (blockIdx.x * 256 + threadIdx.x) * 8;
    size_t row0 = (size_t)blockIdx.y * RB;
    float s[8], s2[8];
#pragma unroll
    for (int u = 0; u < 8; u++) { s[u] = 0.f; s2[u] = 0.f; }
    for (int i = 0; i < RB; i++) {
        bf16x8 v = ld8(X + (row0 + i) * CH + c0);
#pragma unroll
        for (int u = 0; u < 8; u++) {
            float f = (float)v[u];
            s[u] += f; s2[u] += f * f;
        }
    }
    float* dst = part + (size_t)blockIdx.y * (2 * CH);
#pragma unroll
    for (int u = 0; u < 8; u++) {
        dst[c0 + u] = s[u];
        dst[CH + c0 + u] = s2[u];
    }
}

// ---------------- stage B: reduce partials + finalize -> scale/bias ----------------
// ps: post-scale folded into both scale and bias (e.g. 1/sqrt(C) for the energy BN)
__global__ void statsB(const float* __restrict__ part, int P, int nch, float inv_n,
                       float ps, const float* __restrict__ gamma,
                       const float* __restrict__ beta, float* __restrict__ scale,
                       float* __restrict__ bias) {
    int c = blockIdx.x * 256 + threadIdx.x;
    if (c >= nch) return;
    float s = 0.f, s2 = 0.f;
    for (int p = 0; p < P; p++) {
        s += part[(size_t)p * 2 * nch + c];
        s2 += part[(size_t)p * 2 * nch + nch + c];
    }
    float mean = s * inv_n;
    float var = s2 * inv_n - mean * mean;
    float rstd = rsqrtf(var + BNEPS);
    float sc = gamma[c] * rstd;
    scale[c] = sc * ps;
    bias[c] = (beta[c] - mean * sc) * ps;
}

// ---------------- vectorized BN apply (+ReLU) -> bf16 ----------------
template <bool RELU, int CH>
__global__ __launch_bounds__(256) void bn_apply_f32(const float* __restrict__ X,
                                                    bf16* __restrict__ out,
                                                    const float* __restrict__ scale,
                                                    const float* __restrict__ bias) {
    size_t base = ((size_t)blockIdx.x * 256 + threadIdx.x) * 8;
    int c0 = (int)(base & (size_t)(CH - 1));
    f32x4 x0 = ldf4(X + base), x1 = ldf4(X + base + 4);
    f32x4 s0 = ldf4(scale + c0), s1 = ldf4(scale + c0 + 4);
    f32x4 b0 = ldf4(bias + c0), b1 = ldf4(bias + c0 + 4);
    bf16x8 o;
#pragma unroll
    for (int u = 0; u < 4; u++) {
        float v = x0[u] * s0[u] + b0[u];
        if (RELU) v = fmaxf(v, 0.f);
        o[u] = (__bf16)__float2bfloat16(v);
    }
#pragma unroll
    for (int u = 0; u < 4; u++) {
        float v = x1[u] * s1[u] + b1[u];
        if (RELU) v = fmaxf(v, 0.f);
        o[u + 4] = (__bf16)__float2bfloat16(v);
    }
    st8(out + base, o);
}

template <bool RELU, int CH>
__global__ __launch_bounds__(256) void bn_apply_bf16(const bf16* __restrict__ X,
                                                     bf16* __restrict__ out,
                                                     const float* __restrict__ scale,
                                                     const float* __restrict__ bias) {
    size_t base = ((size_t)blockIdx.x * 256 + threadIdx.x) * 8;
    int c0 = (int)(base & (size_t)(CH - 1));
    bf16x8 xv = ld8(X + base);
    f32x4 s0 = ldf4(scale + c0), s1 = ldf4(scale + c0 + 4);
    f32x4 b0 = ldf4(bias + c0), b1 = ldf4(bias + c0 + 4);
    bf16x8 o;
#pragma unroll
    for (int u = 0; u < 4; u++) {
        float v = (float)xv[u] * s0[u] + b0[u];
        if (RELU) v = fmaxf(v, 0.f);
        o[u] = (__bf16)__float2bfloat16(v);
    }
#pragma unroll
    for (int u = 0; u < 4; u++) {
        float v = (float)xv[u + 4] * s1[u] + b1[u];
        if (RELU) v = fmaxf(v, 0.f);
        o[u + 4] = (__bf16)__float2bfloat16(v);
    }
    st8(out + base, o);
}

// =====================================================================================
// LDS-staged 128x128 NT GEMM core (m97 structure): BK=64, global_load_lds width-16
// staging, 4 waves each owning a 64x64 sub-tile (4x4 fragments of 16x16x32 MFMA).
// MODE 0: C -> bf16 (LDS transpose epilogue, 16B stores)
// MODE 1: C + bias + resf -> fp32 (two-half LDS fp32 transpose, f32x4 I/O)
// MODE 2: C + resf -> fp32
// STATS: fuse BN stage-A — per-channel partial sum/sumsq of the stored output tile
// (identical values to a separate statsA pass) -> spart[m-block][2*N] for statsB.
// =====================================================================================
template <int MODE, bool STATS>
__device__ __forceinline__ void gemm_core(const bf16* __restrict__ A,
                                          const bf16* __restrict__ B, int m0, int n0,
                                          int N, int K, const float* __restrict__ bias,
                                          const float* __restrict__ resf,
                                          bf16* __restrict__ outb,
                                          float* __restrict__ outf,
                                          float* __restrict__ spart, char* smem) {
    bf16* As = (bf16*)smem;        // [128][64]
    bf16* Bs = As + 128 * 64;      // [128][64]
    int tid = threadIdx.x;
    int lane = tid & 63, wave = tid >> 6;
    int quad = lane >> 4, l16 = lane & 15;
    int wm = (wave >> 1) * 64, wn = (wave & 1) * 64;
    int srow = lane >> 3;          // 0..7   staging row within 8-row group
    int scol = (lane & 7) * 8;     // 0..56  staging col (elements)
    const bf16* Ab = A + (size_t)m0 * K;
    const bf16* Bb = B + (size_t)n0 * K;
    f32x4 acc[4][4];
#pragma unroll
    for (int i = 0; i < 4; i++)
#pragma unroll
        for (int j = 0; j < 4; j++) acc[i][j] = f32x4{0.f, 0.f, 0.f, 0.f};

    for (int kt = 0; kt < K; kt += 64) {
        if (kt) __syncthreads();  // prior compute done before LDS overwrite
#pragma unroll
        for (int i = 0; i < 4; i++) {
            int r = i * 32 + wave * 8;  // wave-uniform LDS base row
            gload_lds16(Ab + (size_t)(r + srow) * K + kt + scol, As + r * 64);
            gload_lds16(Bb + (size_t)(r + srow) * K + kt + scol, Bs + r * 64);
        }
        __syncthreads();  // compiler drains vmcnt(0) here -> staged data visible
#pragma unroll
        for (int ks = 0; ks < 2; ks++) {
            int kb_ = ks * 32 + quad * 8;
            bf16x8 af[4], bfr[4];
#pragma unroll
            for (int i = 0; i < 4; i++)
                af[i] = ld8(As + (wm + i * 16 + l16) * 64 + kb_);
#pragma unroll
            for (int j = 0; j < 4; j++)
                bfr[j] = ld8(Bs + (wn + j * 16 + l16) * 64 + kb_);
#pragma unroll
            for (int i = 0; i < 4; i++)
#pragma unroll
                for (int j = 0; j < 4; j++)
                    acc[i][j] = __builtin_amdgcn_mfma_f32_16x16x32_bf16(
                        af[i], bfr[j], acc[i][j], 0, 0, 0);
        }
    }
    __syncthreads();  // all LDS reads done before epilogue reuse

    if (MODE == 0) {
        bf16(*Ct)[136] = (bf16(*)[136])smem;  // 128*136*2 = 34816 B
#pragma unroll
        for (int i = 0; i < 4; i++)
#pragma unroll
            for (int j = 0; j < 4; j++)
#pragma unroll
                for (int r = 0; r < 4; r++)
                    Ct[wm + i * 16 + quad * 4 + r][wn + j * 16 + l16] =
                        __float2bfloat16(acc[i][j][r]);
        __syncthreads();
        float s[8], s2[8];
        if (STATS) {
#pragma unroll
            for (int u = 0; u < 8; u++) { s[u] = 0.f; s2[u] = 0.f; }
        }
#pragma unroll
        for (int it = 0; it < 8; it++) {
            int idx = it * 256 + tid;
            int row = idx >> 4, colv = idx & 15;  // colv == tid & 15 (constant)
            bf16x8 c = ld8(&Ct[row][colv * 8]);
            st8(outb + (size_t)(m0 + row) * N + n0 + colv * 8, c);
            if (STATS) {
#pragma unroll
                for (int u = 0; u < 8; u++) {
                    float f = (float)c[u];
                    s[u] += f; s2[u] += f * f;
                }
            }
        }
        if (STATS) {
            __syncthreads();
            float* rf = (float*)smem;  // 256*16*4 = 16 KB
            int g = tid & 15, k = tid >> 4;
#pragma unroll
            for (int u = 0; u < 8; u++) {
                rf[(g * 16 + k) * 16 + u] = s[u];
                rf[(g * 16 + k) * 16 + 8 + u] = s2[u];
            }
            __syncthreads();
            if (tid < 16) {
                float a[8], b[8];
#pragma unroll
                for (int u = 0; u < 8; u++) { a[u] = 0.f; b[u] = 0.f; }
                for (int k2 = 0; k2 < 16; k2++)
#pragma unroll
                    for (int u = 0; u < 8; u++) {
                        a[u] += rf[(tid * 16 + k2) * 16 + u];
                        b[u] += rf[(tid * 16 + k2) * 16 + 8 + u];
                    }
                float* dst = spart + (size_t)(m0 >> 7) * 2 * N + n0 + tid * 8;
#pragma unroll
                for (int u = 0; u < 8; u++) {
                    dst[u] = a[u];
                    dst[N + u] = b[u];
                }
            }
        }
    } else {
        float(*Cf)[132] = (float(*)[132])smem;  // 64*132*4 = 33792 B
        float s[4], s2[4];
        if (STATS) {
#pragma unroll
            for (int u = 0; u < 4; u++) { s[u] = 0.f; s2[u] = 0.f; }
        }
#pragma unroll
        for (int h = 0; h < 2; h++) {
            if (h) __syncthreads();
            if ((wm >> 6) == h) {  // waves owning rows [h*64, h*64+64)
#pragma unroll
                for (int i = 0; i < 4; i++)
#pragma unroll
                    for (int j = 0; j < 4; j++)
#pragma unroll
                        for (int r = 0; r < 4; r++)
                            Cf[i * 16 + quad * 4 + r][wn + j * 16 + l16] = acc[i][j][r];
            }
            __syncthreads();
#pragma unroll
            for (int it = 0; it < 8; it++) {
                int idx = it * 256 + tid;
                int row = idx >> 5, cv = (idx & 31) * 4;  // cv == (tid&31)*4 (constant)
                f32x4 v = ldf4(&Cf[row][cv]);
                int gc = n0 + cv;
                size_t gi = (size_t)(m0 + h * 64 + row) * N + gc;
                f32x4 rr = ldf4(resf + gi);
                if (MODE == 1) {
                    f32x4 bb = ldf4(bias + gc);
                    v = v + bb + rr;
                } else {
                    v = v + rr;
                }
                *reinterpret_cast<f32x4*>(outf + gi) = v;
                if (STATS) {
#pragma unroll
                    for (int u = 0; u < 4; u++) {
                        s[u] += v[u]; s2[u] += v[u] * v[u];
                    }
                }
            }
        }
        if (STATS) {
            __syncthreads();
            float* rf = (float*)smem;  // 256*8*4 = 8 KB
            int g = tid & 31, k = tid >> 5;
#pragma unroll
            for (int u = 0; u < 4; u++) {
                rf[(g * 8 + k) * 8 + u] = s[u];
                rf[(g * 8 + k) * 8 + 4 + u] = s2[u];
            }
            __syncthreads();
            if (tid < 32) {
                float a[4], b[4];
#pragma unroll
                for (int u = 0; u < 4; u++) { a[u] = 0.f; b[u] = 0.f; }
                for (int k2 = 0; k2 < 8; k2++)
#pragma unroll
                    for (int u = 0; u < 4; u++) {
                        a[u] += rf[(tid * 8 + k2) * 8 + u];
                        b[u] += rf[(tid * 8 + k2) * 8 + 4 + u];
                    }
                float* dst = spart + (size_t)(m0 >> 7) * 2 * N + n0 + tid * 4;
#pragma unroll
                for (int u = 0; u < 4; u++) {
                    dst[u] = a[u];
                    dst[N + u] = b[u];
                }
            }
        }
    }
}

template <int MODE, bool STATS>
__global__ __launch_bounds__(256) void gemm128(const bf16* __restrict__ A,
                                               const bf16* __restrict__ B, int N, int K,
                                               const float* __restrict__ bias,
                                               const float* __restrict__ resf,
                                               bf16* __restrict__ outb,
                                               float* __restrict__ outf,
                                               float* __restrict__ spart) {
    __shared__ __align__(16) char smem[34816];
    gemm_core<MODE, STATS>(A, B, blockIdx.x * 128, blockIdx.y * 128, N, K, bias, resf,
                           outb, outf, spart, smem);
}

// QKV fused: Wq|Wk|Wv are contiguous at WB, q|k|v buffers contiguous at qb.
// grid (256, 6): y -> (matrix, 128-col tile)
__global__ __launch_bounds__(256) void gemm_qkv128(const bf16* __restrict__ hbuf,
                                                   const bf16* __restrict__ W,
                                                   bf16* __restrict__ qkv) {
    __shared__ __align__(16) char smem[34816];
    int mat = blockIdx.y >> 1;
    int n0 = (blockIdx.y & 1) * 128;
    gemm_core<0, false>(hbuf, W + mat * 65536, blockIdx.x * 128, n0, CC, CC, nullptr,
                        nullptr, qkv + (size_t)mat * 8388608, nullptr, nullptr, smem);
}

// ---------------- energy = Q K^T per (n,h): one block per nh, 128x128 tile ----------------
__global__ __launch_bounds__(256) void gemm_energy(const bf16* __restrict__ q,
                                                   const bf16* __restrict__ k,
                                                   bf16* __restrict__ E) {
    int nh = blockIdx.x;
    int nb = nh >> 3, hh = nh & 7;
    int tid = threadIdx.x;
    int lane = tid & 63, wave = tid >> 6;
    int quad = lane >> 4, l16 = lane & 15;
    int wm = (wave >> 1) * 64, wn = (wave & 1) * 64;
    size_t tb = (size_t)nb * SS;
    int cb = hh * DD + quad * 8;
    f32x4 zero = {0.f, 0.f, 0.f, 0.f};
    f32x4 acc[4][4];
#pragma unroll
    for (int i = 0; i < 4; i++)
#pragma unroll
        for (int j = 0; j < 4; j++) acc[i][j] = zero;
    bf16x8 af[4], bfg[4];
#pragma unroll
    for (int i = 0; i < 4; i++)
        af[i] = ld8(q + (tb + wm + i * 16 + l16) * CC + cb);
#pragma unroll
    for (int j = 0; j < 4; j++)
        bfg[j] = ld8(k + (tb + wn + j * 16 + l16) * CC + cb);
#pragma unroll
    for (int i = 0; i < 4; i++)
#pragma unroll
        for (int j = 0; j < 4; j++)
            acc[i][j] = __builtin_amdgcn_mfma_f32_16x16x32_bf16(af[i], bfg[j], acc[i][j], 0, 0, 0);
    __shared__ bf16 Et[128][136];
#pragma unroll
    for (int i = 0; i < 4; i++)
#pragma unroll
        for (int j = 0; j < 4; j++)
#pragma unroll
            for (int r = 0; r < 4; r++)
                Et[wm + i * 16 + quad * 4 + r][wn + j * 16 + l16] =
                    __float2bfloat16(acc[i][j][r]);
    __syncthreads();
    bf16* Eb = E + (size_t)nh * SS * SS;
#pragma unroll
    for (int it = 0; it < 8; it++) {
        int idx = it * 256 + tid;
        int row = idx >> 4, colv = idx & 15;
        st8(Eb + (size_t)row * SS + colv * 8, ld8(&Et[row][colv * 8]));
    }
}

// ---------------- BN(energy) + softmax + P V^T per (n,h) ----------------
// P,Vt XOR-swizzled (no padding): LDS = 40960 B -> exactly 4 blocks/CU.
// BN-affine (0.0625 pre-folded in statsB) + softmax fused in registers.
__global__ __launch_bounds__(256, 4) void att_kernel(
    const bf16* __restrict__ E, const bf16* __restrict__ v,
    const float* __restrict__ pe_scale, const float* __restrict__ pe_bias,
    bf16* __restrict__ o) {
    __shared__ bf16 P[SS * 128];   // swizzled [128][128]
    __shared__ bf16 Vt[DD * 128];  // swizzled [32][128]
    int nh = blockIdx.x;
    int nb = nh >> 3, hh = nh & 7;
    const bf16* Eb = E + (size_t)nh * SS * SS;
    int tid = threadIdx.x;
    int wave = tid >> 6, lane = tid & 63;
    // phase 0: transpose token-major v tile into Vt[d][s] (swizzled)
    {
        int s = tid >> 1, d0 = (tid & 1) * 16;
        const bf16* vp = v + (size_t)(nb * SS + s) * CC + hh * DD + d0;
        bf16x8 v0 = ld8(vp), v1 = ld8(vp + 8);
        int g = s >> 3, sub = s & 7;
#pragma unroll
        for (int u = 0; u < 8; u++) {
            int da = d0 + u, db = d0 + 8 + u;
            Vt[da * 128 + swzg(da, g) + sub] = bfc(v0[u]);
            Vt[db * 128 + swzg(db, g) + sub] = bfc(v1[u]);
        }
    }
    // phase A: fused BN + softmax; wave owns rows [wave*32, wave*32+32)
    int rs = lane >> 4, cg = lane & 15;
#pragma unroll
    for (int p = 0; p < 8; p++) {
        int r = wave * 32 + p * 4 + rs;
        int e8 = r * 128 + cg * 8;
        bf16x8 ev = ld8(Eb + e8);
        f32x4 s0 = ldf4(pe_scale + e8), s1 = ldf4(pe_scale + e8 + 4);
        f32x4 b0 = ldf4(pe_bias + e8), b1 = ldf4(pe_bias + e8 + 4);
        float l[8];
#pragma unroll
        for (int u = 0; u < 4; u++) l[u] = (float)ev[u] * s0[u] + b0[u];
#pragma unroll
        for (int u = 0; u < 4; u++) l[u + 4] = (float)ev[u + 4] * s1[u] + b1[u];
        float mx = fmaxf(fmaxf(fmaxf(l[0], l[1]), fmaxf(l[2], l[3])),
                         fmaxf(fmaxf(l[4], l[5]), fmaxf(l[6], l[7])));
#pragma unroll
        for (int off = 8; off; off >>= 1) mx = fmaxf(mx, __shfl_xor(mx, off, 16));
        float e[8], sm = 0.f;
#pragma unroll
        for (int u = 0; u < 8; u++) { e[u] = __expf(l[u] - mx); sm += e[u]; }
#pragma unroll
        for (int off = 8; off; off >>= 1) sm += __shfl_xor(sm, off, 16);
        float inv = 1.0f / sm;
        bf16x8 pv;
#pragma unroll
        for (int u = 0; u < 8; u++) pv[u] = (__bf16)__float2bfloat16(e[u] * inv);
        st8(&P[r * 128 + swzg(r, cg)], pv);
    }
    __syncthreads();  // Vt (cross-thread) visible; P rows are own-wave only
    // phase 3: O = P @ V^T
    int quad = lane >> 4, l16 = lane & 15;
    f32x4 acc[2][2];
#pragma unroll
    for (int i = 0; i < 2; i++)
#pragma unroll
        for (int j = 0; j < 2; j++) acc[i][j] = f32x4{0.f, 0.f, 0.f, 0.f};
#pragma unroll
    for (int kk = 0; kk < SS; kk += 32) {
        int g = (kk >> 3) + quad;  // 16B-group index 0..15
        int r0 = wave * 32 + l16, r1 = r0 + 16;
        bf16x8 a0 = ld8(&P[r0 * 128 + swzg(r0, g)]);
        bf16x8 a1 = ld8(&P[r1 * 128 + swzg(r1, g)]);
        bf16x8 b0 = ld8(&Vt[l16 * 128 + swzg(l16, g)]);
        bf16x8 b1 = ld8(&Vt[(l16 + 16) * 128 + swzg(l16 + 16, g)]);
        acc[0][0] = __builtin_amdgcn_mfma_f32_16x16x32_bf16(a0, b0, acc[0][0], 0, 0, 0);
        acc[0][1] = __builtin_amdgcn_mfma_f32_16x16x32_bf16(a0, b1, acc[0][1], 0, 0, 0);
        acc[1][0] = __builtin_amdgcn_mfma_f32_16x16x32_bf16(a1, b0, acc[1][0], 0, 0, 0);
        acc[1][1] = __builtin_amdgcn_mfma_f32_16x16x32_bf16(a1, b1, acc[1][1], 0, 0, 0);
    }
    __syncthreads();  // all waves done reading P before reuse as O tile
    bf16* Ob = P;     // reuse as [128][40]
#pragma unroll
    for (int i = 0; i < 2; i++)
#pragma unroll
        for (int j = 0; j < 2; j++)
#pragma unroll
            for (int r = 0; r < 4; r++) {
                int row = wave * 32 + i * 16 + quad * 4 + r;
                int col = j * 16 + l16;
                Ob[row * 40 + col] = __float2bfloat16(acc[i][j][r]);
            }
    __syncthreads();
#pragma unroll
    for (int it = 0; it < 2; it++) {
        int idx = it * 256 + tid;
        int row = idx >> 2, colv = idx & 3;
        st8(o + (size_t)(nb * SS + row) * CC + hh * DD + colv * 8,
            ld8(&Ob[row * 40 + colv * 8]));
    }
}

// ---------------- workspace layout (bytes) ----------------
#define WB_OFF 0u
#define HB_OFF 1048576u
#define Q_OFF 17825792u
#define K_OFF 34603008u
#define VT_OFF 51380224u
#define E_OFF 68157440u
#define O_OFF 1048576u      /* reuse hbuf */
#define X1_OFF 17825792u    /* fp32, over q+k */
#define OUT1_OFF 51380224u  /* over v */
#define OUT2_OFF 68157440u  /* over E 1st half */
#define OUT4_OFF 101711872u /* over E 2nd half */
/* transient scale/bias + partial homes (dead windows):
   bn1 s/b  -> E_OFF (2 KB);      x  partial -> E_OFF+64K (256 KB)   [E dead until energy]
   pe  s/b  -> Q_OFF (128 KB);    pe partial -> Q_OFF+128K (4 MB)    [q dead after energy]
   x1 partial -> VT_OFF (512 KB)  [vb dead after att; consumed before out1 write]
   bn0 s/b  -> HB_OFF (2 KB)      [obuf dead after Wo gemm]
   f1  s/b  -> HB_OFF+4K (4 KB);  f1 partial -> HB_OFF+16K (1 MB) */

extern "C" void kernel_launch(void* const* d_in, const int* in_sizes, int n_in,
                              void* d_out, int out_size, void* d_ws, size_t ws_size,
                              hipStream_t stream) {
    const float* x = (const float*)d_in[0];
    const float* g_n = (const float*)d_in[1];
    const float* b_n = (const float*)d_in[2];
    const float* Wq = (const float*)d_in[3];
    const float* Wk = (const float*)d_in[4];
    const float* Wv = (const float*)d_in[5];
    const float* Wo = (const float*)d_in[6];
    const float* bo = (const float*)d_in[7];
    const float* g_pe = (const float*)d_in[8];
    const float* b_pe = (const float*)d_in[9];
    const float* g0 = (const float*)d_in[10];
    const float* b0 = (const float*)d_in[11];
    const float* W0 = (const float*)d_in[12];
    const float* g1 = (const float*)d_in[13];
    const float* b1 = (const float*)d_in[14];
    const float* W1 = (const float*)d_in[15];

    char* ws = (char*)d_ws;
    bf16* WB = (bf16*)(ws + WB_OFF);
    bf16* WOB = WB + 196608;
    bf16* W0B = WB + 262144;
    bf16* W1B = WB + 393216;
    bf16* hbuf = (bf16*)(ws + HB_OFF);
    bf16* qb = (bf16*)(ws + Q_OFF);
    bf16* kb = (bf16*)(ws + K_OFF);
    bf16* vb = (bf16*)(ws + VT_OFF);
    bf16* Ebuf = (bf16*)(ws + E_OFF);
    bf16* obuf = (bf16*)(ws + O_OFF);
    float* x1 = (float*)(ws + X1_OFF);
    bf16* out1 = (bf16*)(ws + OUT1_OFF);
    bf16* out2 = (bf16*)(ws + OUT2_OFF);
    bf16* out4 = (bf16*)(ws + OUT4_OFF);
    float* bn1_scale = (float*)(ws + E_OFF);
    float* bn1_bias = bn1_scale + 256;
    float* xpart = (float*)(ws + E_OFF + 65536);
    float* pe_scale = (float*)(ws + Q_OFF);
    float* pe_bias = pe_scale + 16384;
    float* pepart = (float*)(ws + Q_OFF + 131072);
    float* bn0_scale = (float*)(ws + HB_OFF);
    float* bn0_bias = bn0_scale + 256;
    float* f1_scale = (float*)(ws + HB_OFF + 4096);
    float* f1_bias = f1_scale + 512;
    float* x1part = (float*)(ws + VT_OFF);       // 256*512*4 = 512 KB, vb dead window
    float* f1part = (float*)(ws + HB_OFF + 16384);  // 256*1024*4 = 1 MB, obuf dead
    float* outp = (float*)d_out;

    // weights fp32 -> bf16  ∥  statsA(x)
    prep<<<640, 256, 0, stream>>>(Wq, Wk, Wv, Wo, W0, W1, WB, x, xpart);
    statsB<<<1, 256, 0, stream>>>(xpart, 128, 256, 1.0f / 32768.0f, 1.0f, g_n, b_n,
                                  bn1_scale, bn1_bias);
    bn_apply_f32<false, 256><<<4096, 256, 0, stream>>>(x, hbuf, bn1_scale, bn1_bias);
    // QKV (token-major outputs), LDS-staged 128x128 tiles
    gemm_qkv128<<<dim3(256, 6), 256, 0, stream>>>(hbuf, WB, qb);
    // energy: one block per (n,h)
    gemm_energy<<<NHB, 256, 0, stream>>>(qb, kb, Ebuf);
    // --- BN(energy), 1/sqrt(C) folded into scale/bias ---
    statsA_wide<16384, 32, 2048><<<dim3(8, 32), 256, 0, stream>>>(Ebuf, pepart);
    statsB<<<64, 256, 0, stream>>>(pepart, 32, 16384, 1.0f / 2048.0f, 0.0625f, g_pe,
                                   b_pe, pe_scale, pe_bias);
    // BN + softmax + PV
    att_kernel<<<NHB, 256, 0, stream>>>(Ebuf, vb, pe_scale, pe_bias, obuf);
    // x1 = o @ Wo^T + bo + x (fp32), fused statsA(x1) -> x1part
    gemm128<1, true><<<dim3(256, 2), 256, 0, stream>>>(obuf, WOB, CC, CC, bo, x,
                                                       nullptr, x1, x1part);
    statsB<<<1, 256, 0, stream>>>(x1part, 256, 256, 1.0f / 32768.0f, 1.0f, g0, b0,
                                  bn0_scale, bn0_bias);
    bn_apply_f32<true, 256><<<4096, 256, 0, stream>>>(x1, out1, bn0_scale, bn0_bias);
    // out2 = out1 @ W0^T (bf16), fused statsA(out2) -> f1part
    gemm128<0, true><<<dim3(256, 4), 256, 0, stream>>>(out1, W0B, 2 * CC, CC, nullptr,
                                                       nullptr, out2, nullptr, f1part);
    statsB<<<2, 256, 0, stream>>>(f1part, 256, 512, 1.0f / 32768.0f, 1.0f, g1, b1,
                                  f1_scale, f1_bias);
    bn_apply_bf16<true, 512><<<8192, 256, 0, stream>>>(out2, out4, f1_scale, f1_bias);
    gemm128<2, false><<<dim3(256, 2), 256, 0, stream>>>(out4, W1B, CC, 2 * CC, nullptr,
                                                        x1, nullptr, outp, nullptr);
    (void)in_sizes; (void)n_in; (void)out_size; (void)ws_size;
    (void)kb; (void)vb;
}

// Round 4
// 337.749 us; speedup vs baseline: 1.3439x; 1.3439x over previous
//
#include <hip/hip_runtime.h>
#include <hip/hip_bf16.h>

#define HH 8
#define SS 128
#define CC 256
#define DD 32
#define NTOK 32768
#define NHB 2048
#define BNEPS 1e-5f

using bf16 = __hip_bfloat16;
typedef float f32x4 __attribute__((ext_vector_type(4)));
typedef __bf16 bf16x8 __attribute__((ext_vector_type(8)));

__device__ __forceinline__ bf16x8 ld8(const bf16* p) {
    return *reinterpret_cast<const bf16x8*>(p);
}
__device__ __forceinline__ f32x4 ldf4(const float* p) {
    return *reinterpret_cast<const f32x4*>(p);
}
__device__ __forceinline__ void st8(bf16* p, bf16x8 v) {
    *reinterpret_cast<bf16x8*>(p) = v;
}
// bit-pun __bf16 -> __hip_bfloat16 (avoids ambiguous operator=)
__device__ __forceinline__ bf16 bfc(__bf16 x) {
    union { __bf16 i; bf16 o; } u;
    u.i = x;
    return u.o;
}
// XOR swizzle: 16B-group index g within a 256B row, spread by row low bits.
// Returns element offset of the group start (8 elems = 16B per group).
__device__ __forceinline__ int swzg(int row, int g) {
    return ((g & 8) | ((g & 7) ^ (row & 7))) << 3;
}

// async global->LDS, 16B per lane. LDS dest must be wave-uniform base; lane l
// writes base + l*16 (m104 semantics). Global source is per-lane.
typedef __attribute__((address_space(1))) const void g_void;
typedef __attribute__((address_space(3))) void l_void;
__device__ __forceinline__ void gload_lds16(const bf16* g, bf16* l) {
    __builtin_amdgcn_global_load_lds((g_void*)g, (l_void*)l, 16, 0, 0);
}

// ---------------- prep: fp32->bf16 weight cvt (blocks 0..511) ∥ statsA(x) (blocks 512..639) ----------------
__global__ __launch_bounds__(256) void prep(const float* __restrict__ wq,
                                            const float* __restrict__ wk,
                                            const float* __restrict__ wv,
                                            const float* __restrict__ wo,
                                            const float* __restrict__ w0,
                                            const float* __restrict__ w1,
                                            bf16* __restrict__ out,
                                            const float* __restrict__ X,
                                            float* __restrict__ part) {
    int tid = threadIdx.x;
    if (blockIdx.x < 512) {
        int i = (blockIdx.x * 256 + tid) * 4;  // 0..524284
        const float* src;
        int off;
        if (i < 65536) { src = wq; off = i; }
        else if (i < 131072) { src = wk; off = i - 65536; }
        else if (i < 196608) { src = wv; off = i - 131072; }
        else if (i < 262144) { src = wo; off = i - 196608; }
        else if (i < 393216) { src = w0; off = i - 262144; }
        else { src = w1; off = i - 393216; }
        f32x4 v = ldf4(src + off);
#pragma unroll
        for (int u = 0; u < 4; u++) out[i + u] = __float2bfloat16(v[u]);
        return;
    }
    // statsA for x: CH=256 fp32, P=128 blocks, RB=256 rows, SLOTS=4, ITER=64
    int bx = blockIdx.x - 512;
    int cv = tid & 63, slot = tid >> 6;
    int c0 = cv * 4;
    size_t row0 = (size_t)bx * 256 + slot;
    float s[4], s2[4];
#pragma unroll
    for (int u = 0; u < 4; u++) { s[u] = 0.f; s2[u] = 0.f; }
    for (int i = 0; i < 64; i++) {
        size_t row = row0 + (size_t)i * 4;
        f32x4 v = ldf4(X + row * 256 + c0);
#pragma unroll
        for (int u = 0; u < 4; u++) {
            float f = v[u];
            s[u] += f; s2[u] += f * f;
        }
    }
    __shared__ float red[256][8];
#pragma unroll
    for (int u = 0; u < 4; u++) {
        red[tid][u] = s[u];
        red[tid][4 + u] = s2[u];
    }
    __syncthreads();
    if (tid < 64) {
#pragma unroll
        for (int sl = 1; sl < 4; sl++)
#pragma unroll
            for (int u = 0; u < 4; u++) {
                s[u] += red[tid + sl * 64][u];
                s2[u] += red[tid + sl * 64][4 + u];
            }
        float* dst = part + (size_t)bx * 512;
#pragma unroll
        for (int u = 0; u < 4; u++) {
            dst[c0 + u] = s[u];
            dst[256 + c0 + u] = s2[u];
        }
    }
}

// ---------------- stats stage A (wide CH, bf16): disjoint channels, NO atomics ----------------
template <int CH, int P, int ROWS>
__global__ __launch_bounds__(256) void statsA_wide(const bf16* __restrict__ X,
                                                   float* __restrict__ part) {
    constexpr int RB = ROWS / P;
    int c0 = (blockIdx.x * 256 + threadIdx.x) * 8;
    size_t row0 = (size_t)blockIdx.y * RB;
    float s[8], s2[8];
#pragma unroll
    for (int u = 0; u < 8; u++) { s[u] = 0.f; s2[u] = 0.f; }
    for (int i = 0; i < RB; i++) {
        bf16x8 v = ld8(X + (row0 + i) * CH + c0);
#pragma unroll
        for (int u = 0; u < 8; u++) {
            float f = (float)v[u];
            s[u] += f; s2[u] += f * f;
        }
    }
    float* dst = part + (size_t)blockIdx.y * (2 * CH);
#pragma unroll
    for (int u = 0; u < 8; u++) {
        dst[c0 + u] = s[u];
        dst[CH + c0 + u] = s2[u];
    }
}

// ---------------- stage B: parallel reduce partials + finalize -> scale/bias ----------------
// grid = nch/64 blocks; 256 threads = 64 channels x 4 P-slices; coalesced loads.
// ps: post-scale folded into both scale and bias (e.g. 1/sqrt(C) for the energy BN)
__global__ __launch_bounds__(256) void statsB(const float* __restrict__ part, int P,
                                              int nch, float inv_n, float ps,
                                              const float* __restrict__ gamma,
                                              const float* __restrict__ beta,
                                              float* __restrict__ scale,
                                              float* __restrict__ bias) {
    int cl = threadIdx.x & 63, sl = threadIdx.x >> 6;
    int c = blockIdx.x * 64 + cl;
    float s = 0.f, s2 = 0.f;
    for (int p = sl; p < P; p += 4) {
        s += part[(size_t)p * 2 * nch + c];
        s2 += part[(size_t)p * 2 * nch + nch + c];
    }
    __shared__ float red[2][4][64];
    red[0][sl][cl] = s;
    red[1][sl][cl] = s2;
    __syncthreads();
    if (threadIdx.x < 64) {
        s = red[0][0][cl] + red[0][1][cl] + red[0][2][cl] + red[0][3][cl];
        s2 = red[1][0][cl] + red[1][1][cl] + red[1][2][cl] + red[1][3][cl];
        float mean = s * inv_n;
        float var = s2 * inv_n - mean * mean;
        float rstd = rsqrtf(var + BNEPS);
        float sc = gamma[c] * rstd;
        scale[c] = sc * ps;
        bias[c] = (beta[c] - mean * sc) * ps;
    }
}

// ---------------- vectorized BN apply (+ReLU) -> bf16 ----------------
template <bool RELU, int CH>
__global__ __launch_bounds__(256) void bn_apply_f32(const float* __restrict__ X,
                                                    bf16* __restrict__ out,
                                                    const float* __restrict__ scale,
                                                    const float* __restrict__ bias) {
    size_t base = ((size_t)blockIdx.x * 256 + threadIdx.x) * 8;
    int c0 = (int)(base & (size_t)(CH - 1));
    f32x4 x0 = ldf4(X + base), x1 = ldf4(X + base + 4);
    f32x4 s0 = ldf4(scale + c0), s1 = ldf4(scale + c0 + 4);
    f32x4 b0 = ldf4(bias + c0), b1 = ldf4(bias + c0 + 4);
    bf16x8 o;
#pragma unroll
    for (int u = 0; u < 4; u++) {
        float v = x0[u] * s0[u] + b0[u];
        if (RELU) v = fmaxf(v, 0.f);
        o[u] = (__bf16)__float2bfloat16(v);
    }
#pragma unroll
    for (int u = 0; u < 4; u++) {
        float v = x1[u] * s1[u] + b1[u];
        if (RELU) v = fmaxf(v, 0.f);
        o[u + 4] = (__bf16)__float2bfloat16(v);
    }
    st8(out + base, o);
}

template <bool RELU, int CH>
__global__ __launch_bounds__(256) void bn_apply_bf16(const bf16* __restrict__ X,
                                                     bf16* __restrict__ out,
                                                     const float* __restrict__ scale,
                                                     const float* __restrict__ bias) {
    size_t base = ((size_t)blockIdx.x * 256 + threadIdx.x) * 8;
    int c0 = (int)(base & (size_t)(CH - 1));
    bf16x8 xv = ld8(X + base);
    f32x4 s0 = ldf4(scale + c0), s1 = ldf4(scale + c0 + 4);
    f32x4 b0 = ldf4(bias + c0), b1 = ldf4(bias + c0 + 4);
    bf16x8 o;
#pragma unroll
    for (int u = 0; u < 4; u++) {
        float v = (float)xv[u] * s0[u] + b0[u];
        if (RELU) v = fmaxf(v, 0.f);
        o[u] = (__bf16)__float2bfloat16(v);
    }
#pragma unroll
    for (int u = 0; u < 4; u++) {
        float v = (float)xv[u + 4] * s1[u] + b1[u];
        if (RELU) v = fmaxf(v, 0.f);
        o[u + 4] = (__bf16)__float2bfloat16(v);
    }
    st8(out + base, o);
}

// =====================================================================================
// LDS-staged 128x128 NT GEMM core (m97 structure): BK=64, global_load_lds width-16
// staging, 4 waves each owning a 64x64 sub-tile (4x4 fragments of 16x16x32 MFMA).
// MODE 0: C -> bf16 (LDS transpose epilogue, 16B stores)
// MODE 1: C + bias + resf -> fp32 (two-half LDS fp32 transpose, f32x4 I/O)
// MODE 2: C + resf -> fp32
// STATS: fuse BN stage-A — per-channel partial sum/sumsq of the stored output tile
// (identical values to a separate statsA pass) -> spart[m-block][2*N] for statsB.
// =====================================================================================
template <int MODE, bool STATS>
__device__ __forceinline__ void gemm_core(const bf16* __restrict__ A,
                                          const bf16* __restrict__ B, int m0, int n0,
                                          int N, int K, const float* __restrict__ bias,
                                          const float* __restrict__ resf,
                                          bf16* __restrict__ outb,
                                          float* __restrict__ outf,
                                          float* __restrict__ spart, char* smem) {
    bf16* As = (bf16*)smem;        // [128][64]
    bf16* Bs = As + 128 * 64;      // [128][64]
    int tid = threadIdx.x;
    int lane = tid & 63, wave = tid >> 6;
    int quad = lane >> 4, l16 = lane & 15;
    int wm = (wave >> 1) * 64, wn = (wave & 1) * 64;
    int srow = lane >> 3;          // 0..7   staging row within 8-row group
    int scol = (lane & 7) * 8;     // 0..56  staging col (elements)
    const bf16* Ab = A + (size_t)m0 * K;
    const bf16* Bb = B + (size_t)n0 * K;
    f32x4 acc[4][4];
#pragma unroll
    for (int i = 0; i < 4; i++)
#pragma unroll
        for (int j = 0; j < 4; j++) acc[i][j] = f32x4{0.f, 0.f, 0.f, 0.f};

    for (int kt = 0; kt < K; kt += 64) {
        if (kt) __syncthreads();  // prior compute done before LDS overwrite
#pragma unroll
        for (int i = 0; i < 4; i++) {
            int r = i * 32 + wave * 8;  // wave-uniform LDS base row
            gload_lds16(Ab + (size_t)(r + srow) * K + kt + scol, As + r * 64);
            gload_lds16(Bb + (size_t)(r + srow) * K + kt + scol, Bs + r * 64);
        }
        __syncthreads();  // compiler drains vmcnt(0) here -> staged data visible
#pragma unroll
        for (int ks = 0; ks < 2; ks++) {
            int kb_ = ks * 32 + quad * 8;
            bf16x8 af[4], bfr[4];
#pragma unroll
            for (int i = 0; i < 4; i++)
                af[i] = ld8(As + (wm + i * 16 + l16) * 64 + kb_);
#pragma unroll
            for (int j = 0; j < 4; j++)
                bfr[j] = ld8(Bs + (wn + j * 16 + l16) * 64 + kb_);
#pragma unroll
            for (int i = 0; i < 4; i++)
#pragma unroll
                for (int j = 0; j < 4; j++)
                    acc[i][j] = __builtin_amdgcn_mfma_f32_16x16x32_bf16(
                        af[i], bfr[j], acc[i][j], 0, 0, 0);
        }
    }
    __syncthreads();  // all LDS reads done before epilogue reuse

    if (MODE == 0) {
        bf16(*Ct)[136] = (bf16(*)[136])smem;  // 128*136*2 = 34816 B
#pragma unroll
        for (int i = 0; i < 4; i++)
#pragma unroll
            for (int j = 0; j < 4; j++)
#pragma unroll
                for (int r = 0; r < 4; r++)
                    Ct[wm + i * 16 + quad * 4 + r][wn + j * 16 + l16] =
                        __float2bfloat16(acc[i][j][r]);
        __syncthreads();
        float s[8], s2[8];
        if (STATS) {
#pragma unroll
            for (int u = 0; u < 8; u++) { s[u] = 0.f; s2[u] = 0.f; }
        }
#pragma unroll
        for (int it = 0; it < 8; it++) {
            int idx = it * 256 + tid;
            int row = idx >> 4, colv = idx & 15;  // colv == tid & 15 (constant)
            bf16x8 c = ld8(&Ct[row][colv * 8]);
            st8(outb + (size_t)(m0 + row) * N + n0 + colv * 8, c);
            if (STATS) {
#pragma unroll
                for (int u = 0; u < 8; u++) {
                    float f = (float)c[u];
                    s[u] += f; s2[u] += f * f;
                }
            }
        }
        if (STATS) {
            __syncthreads();
            float* rf = (float*)smem;  // 256*16*4 = 16 KB
            int g = tid & 15, k = tid >> 4;
#pragma unroll
            for (int u = 0; u < 8; u++) {
                rf[(g * 16 + k) * 16 + u] = s[u];
                rf[(g * 16 + k) * 16 + 8 + u] = s2[u];
            }
            __syncthreads();
            if (tid < 16) {
                float a[8], b[8];
#pragma unroll
                for (int u = 0; u < 8; u++) { a[u] = 0.f; b[u] = 0.f; }
                for (int k2 = 0; k2 < 16; k2++)
#pragma unroll
                    for (int u = 0; u < 8; u++) {
                        a[u] += rf[(tid * 16 + k2) * 16 + u];
                        b[u] += rf[(tid * 16 + k2) * 16 + 8 + u];
                    }
                float* dst = spart + (size_t)(m0 >> 7) * 2 * N + n0 + tid * 8;
#pragma unroll
                for (int u = 0; u < 8; u++) {
                    dst[u] = a[u];
                    dst[N + u] = b[u];
                }
            }
        }
    } else {
        float(*Cf)[132] = (float(*)[132])smem;  // 64*132*4 = 33792 B
        float s[4], s2[4];
        if (STATS) {
#pragma unroll
            for (int u = 0; u < 4; u++) { s[u] = 0.f; s2[u] = 0.f; }
        }
#pragma unroll
        for (int h = 0; h < 2; h++) {
            if (h) __syncthreads();
            if ((wm >> 6) == h) {  // waves owning rows [h*64, h*64+64)
#pragma unroll
                for (int i = 0; i < 4; i++)
#pragma unroll
                    for (int j = 0; j < 4; j++)
#pragma unroll
                        for (int r = 0; r < 4; r++)
                            Cf[i * 16 + quad * 4 + r][wn + j * 16 + l16] = acc[i][j][r];
            }
            __syncthreads();
#pragma unroll
            for (int it = 0; it < 8; it++) {
                int idx = it * 256 + tid;
                int row = idx >> 5, cv = (idx & 31) * 4;  // cv == (tid&31)*4 (constant)
                f32x4 v = ldf4(&Cf[row][cv]);
                int gc = n0 + cv;
                size_t gi = (size_t)(m0 + h * 64 + row) * N + gc;
                f32x4 rr = ldf4(resf + gi);
                if (MODE == 1) {
                    f32x4 bb = ldf4(bias + gc);
                    v = v + bb + rr;
                } else {
                    v = v + rr;
                }
                *reinterpret_cast<f32x4*>(outf + gi) = v;
                if (STATS) {
#pragma unroll
                    for (int u = 0; u < 4; u++) {
                        s[u] += v[u]; s2[u] += v[u] * v[u];
                    }
                }
            }
        }
        if (STATS) {
            __syncthreads();
            float* rf = (float*)smem;  // 256*8*4 = 8 KB
            int g = tid & 31, k = tid >> 5;
#pragma unroll
            for (int u = 0; u < 4; u++) {
                rf[(g * 8 + k) * 8 + u] = s[u];
                rf[(g * 8 + k) * 8 + 4 + u] = s2[u];
            }
            __syncthreads();
            if (tid < 32) {
                float a[4], b[4];
#pragma unroll
                for (int u = 0; u < 4; u++) { a[u] = 0.f; b[u] = 0.f; }
                for (int k2 = 0; k2 < 8; k2++)
#pragma unroll
                    for (int u = 0; u < 4; u++) {
                        a[u] += rf[(tid * 8 + k2) * 8 + u];
                        b[u] += rf[(tid * 8 + k2) * 8 + 4 + u];
                    }
                float* dst = spart + (size_t)(m0 >> 7) * 2 * N + n0 + tid * 4;
#pragma unroll
                for (int u = 0; u < 4; u++) {
                    dst[u] = a[u];
                    dst[N + u] = b[u];
                }
            }
        }
    }
}

template <int MODE, bool STATS>
__global__ __launch_bounds__(256) void gemm128(const bf16* __restrict__ A,
                                               const bf16* __restrict__ B, int N, int K,
                                               const float* __restrict__ bias,
                                               const float* __restrict__ resf,
                                               bf16* __restrict__ outb,
                                               float* __restrict__ outf,
                                               float* __restrict__ spart) {
    __shared__ __align__(16) char smem[34816];
    gemm_core<MODE, STATS>(A, B, blockIdx.x * 128, blockIdx.y * 128, N, K, bias, resf,
                           outb, outf, spart, smem);
}

// QKV fused: Wq|Wk|Wv are contiguous at WB, q|k|v buffers contiguous at qb.
// grid (256, 6): y -> (matrix, 128-col tile)
__global__ __launch_bounds__(256) void gemm_qkv128(const bf16* __restrict__ hbuf,
                                                   const bf16* __restrict__ W,
                                                   bf16* __restrict__ qkv) {
    __shared__ __align__(16) char smem[34816];
    int mat = blockIdx.y >> 1;
    int n0 = (blockIdx.y & 1) * 128;
    gemm_core<0, false>(hbuf, W + mat * 65536, blockIdx.x * 128, n0, CC, CC, nullptr,
                        nullptr, qkv + (size_t)mat * 8388608, nullptr, nullptr, smem);
}

// ---------------- energy = Q K^T per (n,h): one block per nh, 128x128 tile ----------------
__global__ __launch_bounds__(256) void gemm_energy(const bf16* __restrict__ q,
                                                   const bf16* __restrict__ k,
                                                   bf16* __restrict__ E) {
    int nh = blockIdx.x;
    int nb = nh >> 3, hh = nh & 7;
    int tid = threadIdx.x;
    int lane = tid & 63, wave = tid >> 6;
    int quad = lane >> 4, l16 = lane & 15;
    int wm = (wave >> 1) * 64, wn = (wave & 1) * 64;
    size_t tb = (size_t)nb * SS;
    int cb = hh * DD + quad * 8;
    f32x4 zero = {0.f, 0.f, 0.f, 0.f};
    f32x4 acc[4][4];
#pragma unroll
    for (int i = 0; i < 4; i++)
#pragma unroll
        for (int j = 0; j < 4; j++) acc[i][j] = zero;
    bf16x8 af[4], bfg[4];
#pragma unroll
    for (int i = 0; i < 4; i++)
        af[i] = ld8(q + (tb + wm + i * 16 + l16) * CC + cb);
#pragma unroll
    for (int j = 0; j < 4; j++)
        bfg[j] = ld8(k + (tb + wn + j * 16 + l16) * CC + cb);
#pragma unroll
    for (int i = 0; i < 4; i++)
#pragma unroll
        for (int j = 0; j < 4; j++)
            acc[i][j] = __builtin_amdgcn_mfma_f32_16x16x32_bf16(af[i], bfg[j], acc[i][j], 0, 0, 0);
    __shared__ bf16 Et[128][136];
#pragma unroll
    for (int i = 0; i < 4; i++)
#pragma unroll
        for (int j = 0; j < 4; j++)
#pragma unroll
            for (int r = 0; r < 4; r++)
                Et[wm + i * 16 + quad * 4 + r][wn + j * 16 + l16] =
                    __float2bfloat16(acc[i][j][r]);
    __syncthreads();
    bf16* Eb = E + (size_t)nh * SS * SS;
#pragma unroll
    for (int it = 0; it < 8; it++) {
        int idx = it * 256 + tid;
        int row = idx >> 4, colv = idx & 15;
        st8(Eb + (size_t)row * SS + colv * 8, ld8(&Et[row][colv * 8]));
    }
}

// ---------------- BN(energy) + softmax + P V^T per (n,h) ----------------
// P,Vt XOR-swizzled (no padding): LDS = 40960 B -> exactly 4 blocks/CU.
// BN-affine (0.0625 pre-folded in statsB) + softmax fused in registers.
__global__ __launch_bounds__(256, 4) void att_kernel(
    const bf16* __restrict__ E, const bf16* __restrict__ v,
    const float* __restrict__ pe_scale, const float* __restrict__ pe_bias,
    bf16* __restrict__ o) {
    __shared__ bf16 P[SS * 128];   // swizzled [128][128]
    __shared__ bf16 Vt[DD * 128];  // swizzled [32][128]
    int nh = blockIdx.x;
    int nb = nh >> 3, hh = nh & 7;
    const bf16* Eb = E + (size_t)nh * SS * SS;
    int tid = threadIdx.x;
    int wave = tid >> 6, lane = tid & 63;
    // phase 0: transpose token-major v tile into Vt[d][s] (swizzled)
    {
        int s = tid >> 1, d0 = (tid & 1) * 16;
        const bf16* vp = v + (size_t)(nb * SS + s) * CC + hh * DD + d0;
        bf16x8 v0 = ld8(vp), v1 = ld8(vp + 8);
        int g = s >> 3, sub = s & 7;
#pragma unroll
        for (int u = 0; u < 8; u++) {
            int da = d0 + u, db = d0 + 8 + u;
            Vt[da * 128 + swzg(da, g) + sub] = bfc(v0[u]);
            Vt[db * 128 + swzg(db, g) + sub] = bfc(v1[u]);
        }
    }
    // phase A: fused BN + softmax; wave owns rows [wave*32, wave*32+32)
    int rs = lane >> 4, cg = lane & 15;
#pragma unroll
    for (int p = 0; p < 8; p++) {
        int r = wave * 32 + p * 4 + rs;
        int e8 = r * 128 + cg * 8;
        bf16x8 ev = ld8(Eb + e8);
        f32x4 s0 = ldf4(pe_scale + e8), s1 = ldf4(pe_scale + e8 + 4);
        f32x4 b0 = ldf4(pe_bias + e8), b1 = ldf4(pe_bias + e8 + 4);
        float l[8];
#pragma unroll
        for (int u = 0; u < 4; u++) l[u] = (float)ev[u] * s0[u] + b0[u];
#pragma unroll
        for (int u = 0; u < 4; u++) l[u + 4] = (float)ev[u + 4] * s1[u] + b1[u];
        float mx = fmaxf(fmaxf(fmaxf(l[0], l[1]), fmaxf(l[2], l[3])),
                         fmaxf(fmaxf(l[4], l[5]), fmaxf(l[6], l[7])));
#pragma unroll
        for (int off = 8; off; off >>= 1) mx = fmaxf(mx, __shfl_xor(mx, off, 16));
        float e[8], sm = 0.f;
#pragma unroll
        for (int u = 0; u < 8; u++) { e[u] = __expf(l[u] - mx); sm += e[u]; }
#pragma unroll
        for (int off = 8; off; off >>= 1) sm += __shfl_xor(sm, off, 16);
        float inv = 1.0f / sm;
        bf16x8 pv;
#pragma unroll
        for (int u = 0; u < 8; u++) pv[u] = (__bf16)__float2bfloat16(e[u] * inv);
        st8(&P[r * 128 + swzg(r, cg)], pv);
    }
    __syncthreads();  // Vt (cross-thread) visible; P rows are own-wave only
    // phase 3: O = P @ V^T
    int quad = lane >> 4, l16 = lane & 15;
    f32x4 acc[2][2];
#pragma unroll
    for (int i = 0; i < 2; i++)
#pragma unroll
        for (int j = 0; j < 2; j++) acc[i][j] = f32x4{0.f, 0.f, 0.f, 0.f};
#pragma unroll
    for (int kk = 0; kk < SS; kk += 32) {
        int g = (kk >> 3) + quad;  // 16B-group index 0..15
        int r0 = wave * 32 + l16, r1 = r0 + 16;
        bf16x8 a0 = ld8(&P[r0 * 128 + swzg(r0, g)]);
        bf16x8 a1 = ld8(&P[r1 * 128 + swzg(r1, g)]);
        bf16x8 b0 = ld8(&Vt[l16 * 128 + swzg(l16, g)]);
        bf16x8 b1 = ld8(&Vt[(l16 + 16) * 128 + swzg(l16 + 16, g)]);
        acc[0][0] = __builtin_amdgcn_mfma_f32_16x16x32_bf16(a0, b0, acc[0][0], 0, 0, 0);
        acc[0][1] = __builtin_amdgcn_mfma_f32_16x16x32_bf16(a0, b1, acc[0][1], 0, 0, 0);
        acc[1][0] = __builtin_amdgcn_mfma_f32_16x16x32_bf16(a1, b0, acc[1][0], 0, 0, 0);
        acc[1][1] = __builtin_amdgcn_mfma_f32_16x16x32_bf16(a1, b1, acc[1][1], 0, 0, 0);
    }
    __syncthreads();  // all waves done reading P before reuse as O tile
    bf16* Ob = P;     // reuse as [128][40]
#pragma unroll
    for (int i = 0; i < 2; i++)
#pragma unroll
        for (int j = 0; j < 2; j++)
#pragma unroll
            for (int r = 0; r < 4; r++) {
                int row = wave * 32 + i * 16 + quad * 4 + r;
                int col = j * 16 + l16;
                Ob[row * 40 + col] = __float2bfloat16(acc[i][j][r]);
            }
    __syncthreads();
#pragma unroll
    for (int it = 0; it < 2; it++) {
        int idx = it * 256 + tid;
        int row = idx >> 2, colv = idx & 3;
        st8(o + (size_t)(nb * SS + row) * CC + hh * DD + colv * 8,
            ld8(&Ob[row * 40 + colv * 8]));
    }
}

// ---------------- workspace layout (bytes) ----------------
#define WB_OFF 0u
#define HB_OFF 1048576u
#define Q_OFF 17825792u
#define K_OFF 34603008u
#define VT_OFF 51380224u
#define E_OFF 68157440u
#define O_OFF 1048576u      /* reuse hbuf */
#define X1_OFF 17825792u    /* fp32, over q+k */
#define OUT1_OFF 51380224u  /* over v */
#define OUT2_OFF 68157440u  /* over E 1st half */
#define OUT4_OFF 101711872u /* over E 2nd half */
/* transient scale/bias + partial homes (dead windows):
   bn1 s/b  -> E_OFF (2 KB);      x  partial -> E_OFF+64K (256 KB)   [E dead until energy]
   pe  s/b  -> Q_OFF (128 KB);    pe partial -> Q_OFF+128K (4 MB)    [q dead after energy]
   x1 partial -> VT_OFF (512 KB)  [vb dead after att; consumed before out1 write]
   bn0 s/b  -> HB_OFF (2 KB)      [obuf dead after Wo gemm]
   f1  s/b  -> HB_OFF+4K (4 KB);  f1 partial -> HB_OFF+16K (1 MB) */

extern "C" void kernel_launch(void* const* d_in, const int* in_sizes, int n_in,
                              void* d_out, int out_size, void* d_ws, size_t ws_size,
                              hipStream_t stream) {
    const float* x = (const float*)d_in[0];
    const float* g_n = (const float*)d_in[1];
    const float* b_n = (const float*)d_in[2];
    const float* Wq = (const float*)d_in[3];
    const float* Wk = (const float*)d_in[4];
    const float* Wv = (const float*)d_in[5];
    const float* Wo = (const float*)d_in[6];
    const float* bo = (const float*)d_in[7];
    const float* g_pe = (const float*)d_in[8];
    const float* b_pe = (const float*)d_in[9];
    const float* g0 = (const float*)d_in[10];
    const float* b0 = (const float*)d_in[11];
    const float* W0 = (const float*)d_in[12];
    const float* g1 = (const float*)d_in[13];
    const float* b1 = (const float*)d_in[14];
    const float* W1 = (const float*)d_in[15];

    char* ws = (char*)d_ws;
    bf16* WB = (bf16*)(ws + WB_OFF);
    bf16* WOB = WB + 196608;
    bf16* W0B = WB + 262144;
    bf16* W1B = WB + 393216;
    bf16* hbuf = (bf16*)(ws + HB_OFF);
    bf16* qb = (bf16*)(ws + Q_OFF);
    bf16* kb = (bf16*)(ws + K_OFF);
    bf16* vb = (bf16*)(ws + VT_OFF);
    bf16* Ebuf = (bf16*)(ws + E_OFF);
    bf16* obuf = (bf16*)(ws + O_OFF);
    float* x1 = (float*)(ws + X1_OFF);
    bf16* out1 = (bf16*)(ws + OUT1_OFF);
    bf16* out2 = (bf16*)(ws + OUT2_OFF);
    bf16* out4 = (bf16*)(ws + OUT4_OFF);
    float* bn1_scale = (float*)(ws + E_OFF);
    float* bn1_bias = bn1_scale + 256;
    float* xpart = (float*)(ws + E_OFF + 65536);
    float* pe_scale = (float*)(ws + Q_OFF);
    float* pe_bias = pe_scale + 16384;
    float* pepart = (float*)(ws + Q_OFF + 131072);
    float* bn0_scale = (float*)(ws + HB_OFF);
    float* bn0_bias = bn0_scale + 256;
    float* f1_scale = (float*)(ws + HB_OFF + 4096);
    float* f1_bias = f1_scale + 512;
    float* x1part = (float*)(ws + VT_OFF);       // 256*512*4 = 512 KB, vb dead window
    float* f1part = (float*)(ws + HB_OFF + 16384);  // 256*1024*4 = 1 MB, obuf dead
    float* outp = (float*)d_out;

    // weights fp32 -> bf16  ∥  statsA(x)
    prep<<<640, 256, 0, stream>>>(Wq, Wk, Wv, Wo, W0, W1, WB, x, xpart);
    statsB<<<4, 256, 0, stream>>>(xpart, 128, 256, 1.0f / 32768.0f, 1.0f, g_n, b_n,
                                  bn1_scale, bn1_bias);
    bn_apply_f32<false, 256><<<4096, 256, 0, stream>>>(x, hbuf, bn1_scale, bn1_bias);
    // QKV (token-major outputs), LDS-staged 128x128 tiles
    gemm_qkv128<<<dim3(256, 6), 256, 0, stream>>>(hbuf, WB, qb);
    // energy: one block per (n,h)
    gemm_energy<<<NHB, 256, 0, stream>>>(qb, kb, Ebuf);
    // --- BN(energy), 1/sqrt(C) folded into scale/bias ---
    statsA_wide<16384, 32, 2048><<<dim3(8, 32), 256, 0, stream>>>(Ebuf, pepart);
    statsB<<<256, 256, 0, stream>>>(pepart, 32, 16384, 1.0f / 2048.0f, 0.0625f, g_pe,
                                    b_pe, pe_scale, pe_bias);
    // BN + softmax + PV
    att_kernel<<<NHB, 256, 0, stream>>>(Ebuf, vb, pe_scale, pe_bias, obuf);
    // x1 = o @ Wo^T + bo + x (fp32), fused statsA(x1) -> x1part
    gemm128<1, true><<<dim3(256, 2), 256, 0, stream>>>(obuf, WOB, CC, CC, bo, x,
                                                       nullptr, x1, x1part);
    statsB<<<4, 256, 0, stream>>>(x1part, 256, 256, 1.0f / 32768.0f, 1.0f, g0, b0,
                                  bn0_scale, bn0_bias);
    bn_apply_f32<true, 256><<<4096, 256, 0, stream>>>(x1, out1, bn0_scale, bn0_bias);
    // out2 = out1 @ W0^T (bf16), fused statsA(out2) -> f1part
    gemm128<0, true><<<dim3(256, 4), 256, 0, stream>>>(out1, W0B, 2 * CC, CC, nullptr,
                                                       nullptr, out2, nullptr, f1part);
    statsB<<<8, 256, 0, stream>>>(f1part, 256, 512, 1.0f / 32768.0f, 1.0f, g1, b1,
                                  f1_scale, f1_bias);
    bn_apply_bf16<true, 512><<<8192, 256, 0, stream>>>(out2, out4, f1_scale, f1_bias);
    gemm128<2, false><<<dim3(256, 2), 256, 0, stream>>>(out4, W1B, CC, 2 * CC, nullptr,
                                                        x1, nullptr, outp, nullptr);
    (void)in_sizes; (void)n_in; (void)out_size; (void)ws_size;
    (void)kb; (void)vb;
}

// Round 5
// 328.625 us; speedup vs baseline: 1.3812x; 1.0278x over previous
//
#include <hip/hip_runtime.h>
#include <hip/hip_bf16.h>

#define HH 8
#define SS 128
#define CC 256
#define DD 32
#define NTOK 32768
#define NHB 2048
#define BNEPS 1e-5f

using bf16 = __hip_bfloat16;
typedef float f32x4 __attribute__((ext_vector_type(4)));
typedef __bf16 bf16x8 __attribute__((ext_vector_type(8)));

__device__ __forceinline__ bf16x8 ld8(const bf16* p) {
    return *reinterpret_cast<const bf16x8*>(p);
}
__device__ __forceinline__ f32x4 ldf4(const float* p) {
    return *reinterpret_cast<const f32x4*>(p);
}
__device__ __forceinline__ void st8(bf16* p, bf16x8 v) {
    *reinterpret_cast<bf16x8*>(p) = v;
}
// bit-pun __bf16 -> __hip_bfloat16 (avoids ambiguous operator=)
__device__ __forceinline__ bf16 bfc(__bf16 x) {
    union { __bf16 i; bf16 o; } u;
    u.i = x;
    return u.o;
}
// XOR swizzle: 16B-group index g within a 256B row, spread by row low bits.
// Returns element offset of the group start (8 elems = 16B per group).
__device__ __forceinline__ int swzg(int row, int g) {
    return ((g & 8) | ((g & 7) ^ (row & 7))) << 3;
}

// async global->LDS, 16B per lane. LDS dest must be wave-uniform base; lane l
// writes base + l*16 (m104 semantics). Global source is per-lane.
typedef __attribute__((address_space(1))) const void g_void;
typedef __attribute__((address_space(3))) void l_void;
__device__ __forceinline__ void gload_lds16(const bf16* g, bf16* l) {
    __builtin_amdgcn_global_load_lds((g_void*)g, (l_void*)l, 16, 0, 0);
}

// ---------------- prep: fp32->bf16 weight cvt (blocks 0..511) ∥ statsA(x) (blocks 512..639) ----------------
__global__ __launch_bounds__(256) void prep(const float* __restrict__ wq,
                                            const float* __restrict__ wk,
                                            const float* __restrict__ wv,
                                            const float* __restrict__ wo,
                                            const float* __restrict__ w0,
                                            const float* __restrict__ w1,
                                            bf16* __restrict__ out,
                                            const float* __restrict__ X,
                                            float* __restrict__ part) {
    int tid = threadIdx.x;
    if (blockIdx.x < 512) {
        int i = (blockIdx.x * 256 + tid) * 4;  // 0..524284
        const float* src;
        int off;
        if (i < 65536) { src = wq; off = i; }
        else if (i < 131072) { src = wk; off = i - 65536; }
        else if (i < 196608) { src = wv; off = i - 131072; }
        else if (i < 262144) { src = wo; off = i - 196608; }
        else if (i < 393216) { src = w0; off = i - 262144; }
        else { src = w1; off = i - 393216; }
        f32x4 v = ldf4(src + off);
#pragma unroll
        for (int u = 0; u < 4; u++) out[i + u] = __float2bfloat16(v[u]);
        return;
    }
    // statsA for x: CH=256 fp32, P=128 blocks, RB=256 rows, SLOTS=4, ITER=64
    int bx = blockIdx.x - 512;
    int cv = tid & 63, slot = tid >> 6;
    int c0 = cv * 4;
    size_t row0 = (size_t)bx * 256 + slot;
    float s[4], s2[4];
#pragma unroll
    for (int u = 0; u < 4; u++) { s[u] = 0.f; s2[u] = 0.f; }
    for (int i = 0; i < 64; i++) {
        size_t row = row0 + (size_t)i * 4;
        f32x4 v = ldf4(X + row * 256 + c0);
#pragma unroll
        for (int u = 0; u < 4; u++) {
            float f = v[u];
            s[u] += f; s2[u] += f * f;
        }
    }
    __shared__ float red[256][8];
#pragma unroll
    for (int u = 0; u < 4; u++) {
        red[tid][u] = s[u];
        red[tid][4 + u] = s2[u];
    }
    __syncthreads();
    if (tid < 64) {
#pragma unroll
        for (int sl = 1; sl < 4; sl++)
#pragma unroll
            for (int u = 0; u < 4; u++) {
                s[u] += red[tid + sl * 64][u];
                s2[u] += red[tid + sl * 64][4 + u];
            }
        float* dst = part + (size_t)bx * 512;
#pragma unroll
        for (int u = 0; u < 4; u++) {
            dst[c0 + u] = s[u];
            dst[256 + c0 + u] = s2[u];
        }
    }
}

// ---------------- stats stage A (wide CH, bf16): disjoint channels, NO atomics ----------------
template <int CH, int P, int ROWS>
__global__ __launch_bounds__(256) void statsA_wide(const bf16* __restrict__ X,
                                                   float* __restrict__ part) {
    constexpr int RB = ROWS / P;
    int c0 = (blockIdx.x * 256 + threadIdx.x) * 8;
    size_t row0 = (size_t)blockIdx.y * RB;
    float s[8], s2[8];
#pragma unroll
    for (int u = 0; u < 8; u++) { s[u] = 0.f; s2[u] = 0.f; }
    for (int i = 0; i < RB; i++) {
        bf16x8 v = ld8(X + (row0 + i) * CH + c0);
#pragma unroll
        for (int u = 0; u < 8; u++) {
            float f = (float)v[u];
            s[u] += f; s2[u] += f * f;
        }
    }
    float* dst = part + (size_t)blockIdx.y * (2 * CH);
#pragma unroll
    for (int u = 0; u < 8; u++) {
        dst[c0 + u] = s[u];
        dst[CH + c0 + u] = s2[u];
    }
}

// ---------------- stage B: parallel reduce partials + finalize -> scale/bias ----------------
// grid = nch/64 blocks; 256 threads = 64 channels x 4 P-slices; coalesced loads.
// ps: post-scale folded into both scale and bias (e.g. 1/sqrt(C) for the energy BN)
__global__ __launch_bounds__(256) void statsB(const float* __restrict__ part, int P,
                                              int nch, float inv_n, float ps,
                                              const float* __restrict__ gamma,
                                              const float* __restrict__ beta,
                                              float* __restrict__ scale,
                                              float* __restrict__ bias) {
    int cl = threadIdx.x & 63, sl = threadIdx.x >> 6;
    int c = blockIdx.x * 64 + cl;
    float s = 0.f, s2 = 0.f;
    for (int p = sl; p < P; p += 4) {
        s += part[(size_t)p * 2 * nch + c];
        s2 += part[(size_t)p * 2 * nch + nch + c];
    }
    __shared__ float red[2][4][64];
    red[0][sl][cl] = s;
    red[1][sl][cl] = s2;
    __syncthreads();
    if (threadIdx.x < 64) {
        s = red[0][0][cl] + red[0][1][cl] + red[0][2][cl] + red[0][3][cl];
        s2 = red[1][0][cl] + red[1][1][cl] + red[1][2][cl] + red[1][3][cl];
        float mean = s * inv_n;
        float var = s2 * inv_n - mean * mean;
        float rstd = rsqrtf(var + BNEPS);
        float sc = gamma[c] * rstd;
        scale[c] = sc * ps;
        bias[c] = (beta[c] - mean * sc) * ps;
    }
}

// =====================================================================================
// LDS-staged 128x128 NT GEMM core (m97 structure): BK=64, 4 waves x (4x4 16x16x32 MFMA).
// B operand: always global_load_lds width-16 direct staging.
// A operand (ASRC): 0 = bf16 direct (gload_lds)
//                   1 = fp32 + fused BN affine           (replaces bn_apply_f32<false>)
//                   2 = fp32 + fused BN affine + ReLU    (replaces bn_apply_f32<true>)
//                   3 = bf16 + fused BN affine + ReLU    (replaces bn_apply_bf16<true>)
// Reg-staged A writes land at the same LDS address gload_lds would (base + lane*16),
// and use the same fp32-fma -> bf16-cvt order as the removed bn_apply kernels.
// MODE 0: C -> bf16; MODE 1: C + bias + resf -> fp32; MODE 2: C + resf -> fp32
// STATS: fuse BN stage-A partial sum/sumsq of output -> spart[m-block][2*N]
// =====================================================================================
template <int MODE, bool STATS, int ASRC>
__device__ __forceinline__ void gemm_core(
    const bf16* __restrict__ A, const float* __restrict__ Af,
    const bf16* __restrict__ B, int m0, int n0, int N, int K,
    const float* __restrict__ a_scale, const float* __restrict__ a_bias,
    const float* __restrict__ bias, const float* __restrict__ resf,
    bf16* __restrict__ outb, float* __restrict__ outf, float* __restrict__ spart,
    char* smem) {
    bf16* As = (bf16*)smem;        // [128][64]
    bf16* Bs = As + 128 * 64;      // [128][64]
    int tid = threadIdx.x;
    int lane = tid & 63, wave = tid >> 6;
    int quad = lane >> 4, l16 = lane & 15;
    int wm = (wave >> 1) * 64, wn = (wave & 1) * 64;
    int srow = lane >> 3;          // 0..7   staging row within 8-row group
    int scol = (lane & 7) * 8;     // 0..56  staging col (elements)
    const bf16* Ab = (ASRC == 0) ? A + (size_t)m0 * K : A;
    const bf16* Bb = B + (size_t)n0 * K;
    f32x4 acc[4][4];
#pragma unroll
    for (int i = 0; i < 4; i++)
#pragma unroll
        for (int j = 0; j < 4; j++) acc[i][j] = f32x4{0.f, 0.f, 0.f, 0.f};

    for (int kt = 0; kt < K; kt += 64) {
        if (kt) __syncthreads();  // prior compute done before LDS overwrite
        // B: async direct staging (issued first so loads fly under A work)
#pragma unroll
        for (int i = 0; i < 4; i++) {
            int r = i * 32 + wave * 8;  // wave-uniform LDS base row
            gload_lds16(Bb + (size_t)(r + srow) * K + kt + scol, Bs + r * 64);
        }
        if (ASRC == 0) {
#pragma unroll
            for (int i = 0; i < 4; i++) {
                int r = i * 32 + wave * 8;
                gload_lds16(Ab + (size_t)(r + srow) * K + kt + scol, As + r * 64);
            }
        } else {
            int c = kt + scol;
            f32x4 s0 = ldf4(a_scale + c), s1 = ldf4(a_scale + c + 4);
            f32x4 b0 = ldf4(a_bias + c), b1 = ldf4(a_bias + c + 4);
#pragma unroll
            for (int i = 0; i < 4; i++) {
                int r = i * 32 + wave * 8;
                size_t row = (size_t)(m0 + r + srow);
                bf16x8 av;
                if (ASRC == 3) {
                    bf16x8 xv = ld8(Ab + row * K + c);
#pragma unroll
                    for (int u = 0; u < 4; u++) {
                        float f = (float)xv[u] * s0[u] + b0[u];
                        f = fmaxf(f, 0.f);
                        av[u] = (__bf16)__float2bfloat16(f);
                    }
#pragma unroll
                    for (int u = 0; u < 4; u++) {
                        float f = (float)xv[u + 4] * s1[u] + b1[u];
                        f = fmaxf(f, 0.f);
                        av[u + 4] = (__bf16)__float2bfloat16(f);
                    }
                } else {
                    f32x4 x0 = ldf4(Af + row * K + c), x1v = ldf4(Af + row * K + c + 4);
#pragma unroll
                    for (int u = 0; u < 4; u++) {
                        float f = x0[u] * s0[u] + b0[u];
                        if (ASRC == 2) f = fmaxf(f, 0.f);
                        av[u] = (__bf16)__float2bfloat16(f);
                    }
#pragma unroll
                    for (int u = 0; u < 4; u++) {
                        float f = x1v[u] * s1[u] + b1[u];
                        if (ASRC == 2) f = fmaxf(f, 0.f);
                        av[u + 4] = (__bf16)__float2bfloat16(f);
                    }
                }
                st8(As + r * 64 + lane * 8, av);  // == (r+srow)*64 + scol
            }
        }
        __syncthreads();  // drains vmcnt + lgkm -> staged data visible
#pragma unroll
        for (int ks = 0; ks < 2; ks++) {
            int kb_ = ks * 32 + quad * 8;
            bf16x8 af[4], bfr[4];
#pragma unroll
            for (int i = 0; i < 4; i++)
                af[i] = ld8(As + (wm + i * 16 + l16) * 64 + kb_);
#pragma unroll
            for (int j = 0; j < 4; j++)
                bfr[j] = ld8(Bs + (wn + j * 16 + l16) * 64 + kb_);
#pragma unroll
            for (int i = 0; i < 4; i++)
#pragma unroll
                for (int j = 0; j < 4; j++)
                    acc[i][j] = __builtin_amdgcn_mfma_f32_16x16x32_bf16(
                        af[i], bfr[j], acc[i][j], 0, 0, 0);
        }
    }
    __syncthreads();  // all LDS reads done before epilogue reuse

    if (MODE == 0) {
        bf16(*Ct)[136] = (bf16(*)[136])smem;  // 128*136*2 = 34816 B
#pragma unroll
        for (int i = 0; i < 4; i++)
#pragma unroll
            for (int j = 0; j < 4; j++)
#pragma unroll
                for (int r = 0; r < 4; r++)
                    Ct[wm + i * 16 + quad * 4 + r][wn + j * 16 + l16] =
                        __float2bfloat16(acc[i][j][r]);
        __syncthreads();
        float s[8], s2[8];
        if (STATS) {
#pragma unroll
            for (int u = 0; u < 8; u++) { s[u] = 0.f; s2[u] = 0.f; }
        }
#pragma unroll
        for (int it = 0; it < 8; it++) {
            int idx = it * 256 + tid;
            int row = idx >> 4, colv = idx & 15;  // colv == tid & 15 (constant)
            bf16x8 c = ld8(&Ct[row][colv * 8]);
            st8(outb + (size_t)(m0 + row) * N + n0 + colv * 8, c);
            if (STATS) {
#pragma unroll
                for (int u = 0; u < 8; u++) {
                    float f = (float)c[u];
                    s[u] += f; s2[u] += f * f;
                }
            }
        }
        if (STATS) {
            __syncthreads();
            float* rf = (float*)smem;  // 256*16*4 = 16 KB
            int g = tid & 15, k = tid >> 4;
#pragma unroll
            for (int u = 0; u < 8; u++) {
                rf[(g * 16 + k) * 16 + u] = s[u];
                rf[(g * 16 + k) * 16 + 8 + u] = s2[u];
            }
            __syncthreads();
            if (tid < 16) {
                float a[8], b[8];
#pragma unroll
                for (int u = 0; u < 8; u++) { a[u] = 0.f; b[u] = 0.f; }
                for (int k2 = 0; k2 < 16; k2++)
#pragma unroll
                    for (int u = 0; u < 8; u++) {
                        a[u] += rf[(tid * 16 + k2) * 16 + u];
                        b[u] += rf[(tid * 16 + k2) * 16 + 8 + u];
                    }
                float* dst = spart + (size_t)(m0 >> 7) * 2 * N + n0 + tid * 8;
#pragma unroll
                for (int u = 0; u < 8; u++) {
                    dst[u] = a[u];
                    dst[N + u] = b[u];
                }
            }
        }
    } else {
        float(*Cf)[132] = (float(*)[132])smem;  // 64*132*4 = 33792 B
        float s[4], s2[4];
        if (STATS) {
#pragma unroll
            for (int u = 0; u < 4; u++) { s[u] = 0.f; s2[u] = 0.f; }
        }
#pragma unroll
        for (int h = 0; h < 2; h++) {
            if (h) __syncthreads();
            if ((wm >> 6) == h) {  // waves owning rows [h*64, h*64+64)
#pragma unroll
                for (int i = 0; i < 4; i++)
#pragma unroll
                    for (int j = 0; j < 4; j++)
#pragma unroll
                        for (int r = 0; r < 4; r++)
                            Cf[i * 16 + quad * 4 + r][wn + j * 16 + l16] = acc[i][j][r];
            }
            __syncthreads();
#pragma unroll
            for (int it = 0; it < 8; it++) {
                int idx = it * 256 + tid;
                int row = idx >> 5, cv = (idx & 31) * 4;  // cv == (tid&31)*4 (constant)
                f32x4 v = ldf4(&Cf[row][cv]);
                int gc = n0 + cv;
                size_t gi = (size_t)(m0 + h * 64 + row) * N + gc;
                f32x4 rr = ldf4(resf + gi);
                if (MODE == 1) {
                    f32x4 bb = ldf4(bias + gc);
                    v = v + bb + rr;
                } else {
                    v = v + rr;
                }
                *reinterpret_cast<f32x4*>(outf + gi) = v;
                if (STATS) {
#pragma unroll
                    for (int u = 0; u < 4; u++) {
                        s[u] += v[u]; s2[u] += v[u] * v[u];
                    }
                }
            }
        }
        if (STATS) {
            __syncthreads();
            float* rf = (float*)smem;  // 256*8*4 = 8 KB
            int g = tid & 31, k = tid >> 5;
#pragma unroll
            for (int u = 0; u < 4; u++) {
                rf[(g * 8 + k) * 8 + u] = s[u];
                rf[(g * 8 + k) * 8 + 4 + u] = s2[u];
            }
            __syncthreads();
            if (tid < 32) {
                float a[4], b[4];
#pragma unroll
                for (int u = 0; u < 4; u++) { a[u] = 0.f; b[u] = 0.f; }
                for (int k2 = 0; k2 < 8; k2++)
#pragma unroll
                    for (int u = 0; u < 4; u++) {
                        a[u] += rf[(tid * 8 + k2) * 8 + u];
                        b[u] += rf[(tid * 8 + k2) * 8 + 4 + u];
                    }
                float* dst = spart + (size_t)(m0 >> 7) * 2 * N + n0 + tid * 4;
#pragma unroll
                for (int u = 0; u < 4; u++) {
                    dst[u] = a[u];
                    dst[N + u] = b[u];
                }
            }
        }
    }
}

template <int MODE, bool STATS, int ASRC>
__global__ __launch_bounds__(256) void gemm128(
    const bf16* __restrict__ A, const float* __restrict__ Af,
    const bf16* __restrict__ B, int N, int K, const float* __restrict__ a_scale,
    const float* __restrict__ a_bias, const float* __restrict__ bias,
    const float* __restrict__ resf, bf16* __restrict__ outb,
    float* __restrict__ outf, float* __restrict__ spart) {
    __shared__ __align__(16) char smem[34816];
    gemm_core<MODE, STATS, ASRC>(A, Af, B, blockIdx.x * 128, blockIdx.y * 128, N, K,
                                 a_scale, a_bias, bias, resf, outb, outf, spart, smem);
}

// QKV fused: A = BN(x) computed in staging from fp32 x + bn1 scale/bias.
// Wq|Wk|Wv contiguous at WB, q|k|v buffers contiguous at qb. grid (256, 6).
__global__ __launch_bounds__(256) void gemm_qkv128(const float* __restrict__ x,
                                                   const bf16* __restrict__ W,
                                                   const float* __restrict__ a_scale,
                                                   const float* __restrict__ a_bias,
                                                   bf16* __restrict__ qkv) {
    __shared__ __align__(16) char smem[34816];
    int mat = blockIdx.y >> 1;
    int n0 = (blockIdx.y & 1) * 128;
    gemm_core<0, false, 1>(nullptr, x, W + mat * 65536, blockIdx.x * 128, n0, CC, CC,
                           a_scale, a_bias, nullptr, nullptr,
                           qkv + (size_t)mat * 8388608, nullptr, nullptr, smem);
}

// ---------------- energy = Q K^T per (n,h): one block per nh, 128x128 tile ----------------
__global__ __launch_bounds__(256) void gemm_energy(const bf16* __restrict__ q,
                                                   const bf16* __restrict__ k,
                                                   bf16* __restrict__ E) {
    int nh = blockIdx.x;
    int nb = nh >> 3, hh = nh & 7;
    int tid = threadIdx.x;
    int lane = tid & 63, wave = tid >> 6;
    int quad = lane >> 4, l16 = lane & 15;
    int wm = (wave >> 1) * 64, wn = (wave & 1) * 64;
    size_t tb = (size_t)nb * SS;
    int cb = hh * DD + quad * 8;
    f32x4 zero = {0.f, 0.f, 0.f, 0.f};
    f32x4 acc[4][4];
#pragma unroll
    for (int i = 0; i < 4; i++)
#pragma unroll
        for (int j = 0; j < 4; j++) acc[i][j] = zero;
    bf16x8 af[4], bfg[4];
#pragma unroll
    for (int i = 0; i < 4; i++)
        af[i] = ld8(q + (tb + wm + i * 16 + l16) * CC + cb);
#pragma unroll
    for (int j = 0; j < 4; j++)
        bfg[j] = ld8(k + (tb + wn + j * 16 + l16) * CC + cb);
#pragma unroll
    for (int i = 0; i < 4; i++)
#pragma unroll
        for (int j = 0; j < 4; j++)
            acc[i][j] = __builtin_amdgcn_mfma_f32_16x16x32_bf16(af[i], bfg[j], acc[i][j], 0, 0, 0);
    __shared__ bf16 Et[128][136];
#pragma unroll
    for (int i = 0; i < 4; i++)
#pragma unroll
        for (int j = 0; j < 4; j++)
#pragma unroll
            for (int r = 0; r < 4; r++)
                Et[wm + i * 16 + quad * 4 + r][wn + j * 16 + l16] =
                    __float2bfloat16(acc[i][j][r]);
    __syncthreads();
    bf16* Eb = E + (size_t)nh * SS * SS;
#pragma unroll
    for (int it = 0; it < 8; it++) {
        int idx = it * 256 + tid;
        int row = idx >> 4, colv = idx & 15;
        st8(Eb + (size_t)row * SS + colv * 8, ld8(&Et[row][colv * 8]));
    }
}

// ---------------- BN(energy) + softmax + P V^T per (n,h) ----------------
// P,Vt XOR-swizzled (no padding): LDS = 40960 B -> exactly 4 blocks/CU.
// BN-affine (0.0625 pre-folded in statsB) + softmax fused in registers.
__global__ __launch_bounds__(256, 4) void att_kernel(
    const bf16* __restrict__ E, const bf16* __restrict__ v,
    const float* __restrict__ pe_scale, const float* __restrict__ pe_bias,
    bf16* __restrict__ o) {
    __shared__ bf16 P[SS * 128];   // swizzled [128][128]
    __shared__ bf16 Vt[DD * 128];  // swizzled [32][128]
    int nh = blockIdx.x;
    int nb = nh >> 3, hh = nh & 7;
    const bf16* Eb = E + (size_t)nh * SS * SS;
    int tid = threadIdx.x;
    int wave = tid >> 6, lane = tid & 63;
    // phase 0: transpose token-major v tile into Vt[d][s] (swizzled)
    {
        int s = tid >> 1, d0 = (tid & 1) * 16;
        const bf16* vp = v + (size_t)(nb * SS + s) * CC + hh * DD + d0;
        bf16x8 v0 = ld8(vp), v1 = ld8(vp + 8);
        int g = s >> 3, sub = s & 7;
#pragma unroll
        for (int u = 0; u < 8; u++) {
            int da = d0 + u, db = d0 + 8 + u;
            Vt[da * 128 + swzg(da, g) + sub] = bfc(v0[u]);
            Vt[db * 128 + swzg(db, g) + sub] = bfc(v1[u]);
        }
    }
    // phase A: fused BN + softmax; wave owns rows [wave*32, wave*32+32)
    int rs = lane >> 4, cg = lane & 15;
#pragma unroll
    for (int p = 0; p < 8; p++) {
        int r = wave * 32 + p * 4 + rs;
        int e8 = r * 128 + cg * 8;
        bf16x8 ev = ld8(Eb + e8);
        f32x4 s0 = ldf4(pe_scale + e8), s1 = ldf4(pe_scale + e8 + 4);
        f32x4 b0 = ldf4(pe_bias + e8), b1 = ldf4(pe_bias + e8 + 4);
        float l[8];
#pragma unroll
        for (int u = 0; u < 4; u++) l[u] = (float)ev[u] * s0[u] + b0[u];
#pragma unroll
        for (int u = 0; u < 4; u++) l[u + 4] = (float)ev[u + 4] * s1[u] + b1[u];
        float mx = fmaxf(fmaxf(fmaxf(l[0], l[1]), fmaxf(l[2], l[3])),
                         fmaxf(fmaxf(l[4], l[5]), fmaxf(l[6], l[7])));
#pragma unroll
        for (int off = 8; off; off >>= 1) mx = fmaxf(mx, __shfl_xor(mx, off, 16));
        float e[8], sm = 0.f;
#pragma unroll
        for (int u = 0; u < 8; u++) { e[u] = __expf(l[u] - mx); sm += e[u]; }
#pragma unroll
        for (int off = 8; off; off >>= 1) sm += __shfl_xor(sm, off, 16);
        float inv = 1.0f / sm;
        bf16x8 pv;
#pragma unroll
        for (int u = 0; u < 8; u++) pv[u] = (__bf16)__float2bfloat16(e[u] * inv);
        st8(&P[r * 128 + swzg(r, cg)], pv);
    }
    __syncthreads();  // Vt (cross-thread) visible; P rows are own-wave only
    // phase 3: O = P @ V^T
    int quad = lane >> 4, l16 = lane & 15;
    f32x4 acc[2][2];
#pragma unroll
    for (int i = 0; i < 2; i++)
#pragma unroll
        for (int j = 0; j < 2; j++) acc[i][j] = f32x4{0.f, 0.f, 0.f, 0.f};
#pragma unroll
    for (int kk = 0; kk < SS; kk += 32) {
        int g = (kk >> 3) + quad;  // 16B-group index 0..15
        int r0 = wave * 32 + l16, r1 = r0 + 16;
        bf16x8 a0 = ld8(&P[r0 * 128 + swzg(r0, g)]);
        bf16x8 a1 = ld8(&P[r1 * 128 + swzg(r1, g)]);
        bf16x8 b0 = ld8(&Vt[l16 * 128 + swzg(l16, g)]);
        bf16x8 b1 = ld8(&Vt[(l16 + 16) * 128 + swzg(l16 + 16, g)]);
        acc[0][0] = __builtin_amdgcn_mfma_f32_16x16x32_bf16(a0, b0, acc[0][0], 0, 0, 0);
        acc[0][1] = __builtin_amdgcn_mfma_f32_16x16x32_bf16(a0, b1, acc[0][1], 0, 0, 0);
        acc[1][0] = __builtin_amdgcn_mfma_f32_16x16x32_bf16(a1, b0, acc[1][0], 0, 0, 0);
        acc[1][1] = __builtin_amdgcn_mfma_f32_16x16x32_bf16(a1, b1, acc[1][1], 0, 0, 0);
    }
    __syncthreads();  // all waves done reading P before reuse as O tile
    bf16* Ob = P;     // reuse as [128][40]
#pragma unroll
    for (int i = 0; i < 2; i++)
#pragma unroll
        for (int j = 0; j < 2; j++)
#pragma unroll
            for (int r = 0; r < 4; r++) {
                int row = wave * 32 + i * 16 + quad * 4 + r;
                int col = j * 16 + l16;
                Ob[row * 40 + col] = __float2bfloat16(acc[i][j][r]);
            }
    __syncthreads();
#pragma unroll
    for (int it = 0; it < 2; it++) {
        int idx = it * 256 + tid;
        int row = idx >> 2, colv = idx & 3;
        st8(o + (size_t)(nb * SS + row) * CC + hh * DD + colv * 8,
            ld8(&Ob[row * 40 + colv * 8]));
    }
}

// ---------------- workspace layout (bytes) ----------------
#define WB_OFF 0u
#define O_OFF 1048576u      /* obuf bf16 16.7MB */
#define Q_OFF 17825792u
#define K_OFF 34603008u
#define VT_OFF 51380224u
#define E_OFF 68157440u
#define X1_OFF 17825792u    /* fp32, over q+k */
#define OUT2_OFF 68157440u  /* over E 1st half (E dead after att) */
/* transient scale/bias + partial homes (dead windows):
   bn1 s/b  -> E_OFF (2 KB);      x  partial -> E_OFF+64K (256 KB)  [E dead until energy]
   pe  s/b  -> Q_OFF (128 KB);    pe partial -> Q_OFF+128K (4 MB)   [q dead after energy]
   x1 partial -> VT_OFF (512 KB)  [vb dead after att]
   bn0 s/b  -> O_OFF (2 KB)       [obuf dead after Wo gemm]
   f1  s/b  -> O_OFF+4K (4 KB);   f1 partial -> O_OFF+16K (1 MB) */

extern "C" void kernel_launch(void* const* d_in, const int* in_sizes, int n_in,
                              void* d_out, int out_size, void* d_ws, size_t ws_size,
                              hipStream_t stream) {
    const float* x = (const float*)d_in[0];
    const float* g_n = (const float*)d_in[1];
    const float* b_n = (const float*)d_in[2];
    const float* Wq = (const float*)d_in[3];
    const float* Wk = (const float*)d_in[4];
    const float* Wv = (const float*)d_in[5];
    const float* Wo = (const float*)d_in[6];
    const float* bo = (const float*)d_in[7];
    const float* g_pe = (const float*)d_in[8];
    const float* b_pe = (const float*)d_in[9];
    const float* g0 = (const float*)d_in[10];
    const float* b0 = (const float*)d_in[11];
    const float* W0 = (const float*)d_in[12];
    const float* g1 = (const float*)d_in[13];
    const float* b1 = (const float*)d_in[14];
    const float* W1 = (const float*)d_in[15];

    char* ws = (char*)d_ws;
    bf16* WB = (bf16*)(ws + WB_OFF);
    bf16* WOB = WB + 196608;
    bf16* W0B = WB + 262144;
    bf16* W1B = WB + 393216;
    bf16* qb = (bf16*)(ws + Q_OFF);
    bf16* kb = (bf16*)(ws + K_OFF);
    bf16* vb = (bf16*)(ws + VT_OFF);
    bf16* Ebuf = (bf16*)(ws + E_OFF);
    bf16* obuf = (bf16*)(ws + O_OFF);
    float* x1 = (float*)(ws + X1_OFF);
    bf16* out2 = (bf16*)(ws + OUT2_OFF);
    float* bn1_scale = (float*)(ws + E_OFF);
    float* bn1_bias = bn1_scale + 256;
    float* xpart = (float*)(ws + E_OFF + 65536);
    float* pe_scale = (float*)(ws + Q_OFF);
    float* pe_bias = pe_scale + 16384;
    float* pepart = (float*)(ws + Q_OFF + 131072);
    float* bn0_scale = (float*)(ws + O_OFF);
    float* bn0_bias = bn0_scale + 256;
    float* f1_scale = (float*)(ws + O_OFF + 4096);
    float* f1_bias = f1_scale + 512;
    float* x1part = (float*)(ws + VT_OFF);          // 512 KB, vb dead window
    float* f1part = (float*)(ws + O_OFF + 16384);   // 1 MB, obuf dead
    float* outp = (float*)d_out;

    // weights fp32 -> bf16  ∥  statsA(x)
    prep<<<640, 256, 0, stream>>>(Wq, Wk, Wv, Wo, W0, W1, WB, x, xpart);
    statsB<<<4, 256, 0, stream>>>(xpart, 128, 256, 1.0f / 32768.0f, 1.0f, g_n, b_n,
                                  bn1_scale, bn1_bias);
    // QKV with fused BN(x) in A-staging (token-major outputs)
    gemm_qkv128<<<dim3(256, 6), 256, 0, stream>>>(x, WB, bn1_scale, bn1_bias, qb);
    // energy: one block per (n,h)
    gemm_energy<<<NHB, 256, 0, stream>>>(qb, kb, Ebuf);
    // --- BN(energy), 1/sqrt(C) folded into scale/bias ---
    statsA_wide<16384, 32, 2048><<<dim3(8, 32), 256, 0, stream>>>(Ebuf, pepart);
    statsB<<<256, 256, 0, stream>>>(pepart, 32, 16384, 1.0f / 2048.0f, 0.0625f, g_pe,
                                    b_pe, pe_scale, pe_bias);
    // BN + softmax + PV
    att_kernel<<<NHB, 256, 0, stream>>>(Ebuf, vb, pe_scale, pe_bias, obuf);
    // x1 = o @ Wo^T + bo + x (fp32), fused statsA(x1) -> x1part
    gemm128<1, true, 0><<<dim3(256, 2), 256, 0, stream>>>(
        obuf, nullptr, WOB, CC, CC, nullptr, nullptr, bo, x, nullptr, x1, x1part);
    statsB<<<4, 256, 0, stream>>>(x1part, 256, 256, 1.0f / 32768.0f, 1.0f, g0, b0,
                                  bn0_scale, bn0_bias);
    // out2 = relu(BN(x1)) @ W0^T (BN fused in A-staging), fused statsA(out2) -> f1part
    gemm128<0, true, 2><<<dim3(256, 4), 256, 0, stream>>>(
        nullptr, x1, W0B, 2 * CC, CC, bn0_scale, bn0_bias, nullptr, nullptr, out2,
        nullptr, f1part);
    statsB<<<8, 256, 0, stream>>>(f1part, 256, 512, 1.0f / 32768.0f, 1.0f, g1, b1,
                                  f1_scale, f1_bias);
    // out = relu(BN(out2)) @ W1^T + x1 (BN fused in A-staging), fp32 out
    gemm128<2, false, 3><<<dim3(256, 2), 256, 0, stream>>>(
        out2, nullptr, W1B, CC, 2 * CC, f1_scale, f1_bias, nullptr, x1, nullptr, outp,
        nullptr);
    (void)in_sizes; (void)n_in; (void)out_size; (void)ws_size;
    (void)kb; (void)vb;
}

// Round 6
// 320.144 us; speedup vs baseline: 1.4178x; 1.0265x over previous
//
#include <hip/hip_runtime.h>
#include <hip/hip_bf16.h>

#define HH 8
#define SS 128
#define CC 256
#define DD 32
#define NTOK 32768
#define NHB 2048
#define BNEPS 1e-5f

using bf16 = __hip_bfloat16;
typedef float f32x4 __attribute__((ext_vector_type(4)));
typedef __bf16 bf16x8 __attribute__((ext_vector_type(8)));

__device__ __forceinline__ bf16x8 ld8(const bf16* p) {
    return *reinterpret_cast<const bf16x8*>(p);
}
__device__ __forceinline__ f32x4 ldf4(const float* p) {
    return *reinterpret_cast<const f32x4*>(p);
}
__device__ __forceinline__ void st8(bf16* p, bf16x8 v) {
    *reinterpret_cast<bf16x8*>(p) = v;
}
// bit-pun __bf16 -> __hip_bfloat16 (avoids ambiguous operator=)
__device__ __forceinline__ bf16 bfc(__bf16 x) {
    union { __bf16 i; bf16 o; } u;
    u.i = x;
    return u.o;
}
// XOR swizzle: 16B-group index g within a 256B row, spread by row low bits.
// Returns element offset of the group start (8 elems = 16B per group).
__device__ __forceinline__ int swzg(int row, int g) {
    return ((g & 8) | ((g & 7) ^ (row & 7))) << 3;
}

// async global->LDS, 16B per lane. LDS dest must be wave-uniform base; lane l
// writes base + l*16 (m104 semantics). Global source is per-lane.
typedef __attribute__((address_space(1))) const void g_void;
typedef __attribute__((address_space(3))) void l_void;
__device__ __forceinline__ void gload_lds16(const bf16* g, bf16* l) {
    __builtin_amdgcn_global_load_lds((g_void*)g, (l_void*)l, 16, 0, 0);
}

// ---------------- prep: fp32->bf16 weight cvt (blocks 0..511) ∥ statsA(x) (blocks 512..639) ----------------
__global__ __launch_bounds__(256) void prep(const float* __restrict__ wq,
                                            const float* __restrict__ wk,
                                            const float* __restrict__ wv,
                                            const float* __restrict__ wo,
                                            const float* __restrict__ w0,
                                            const float* __restrict__ w1,
                                            bf16* __restrict__ out,
                                            const float* __restrict__ X,
                                            float* __restrict__ part) {
    int tid = threadIdx.x;
    if (blockIdx.x < 512) {
        int i = (blockIdx.x * 256 + tid) * 4;  // 0..524284
        const float* src;
        int off;
        if (i < 65536) { src = wq; off = i; }
        else if (i < 131072) { src = wk; off = i - 65536; }
        else if (i < 196608) { src = wv; off = i - 131072; }
        else if (i < 262144) { src = wo; off = i - 196608; }
        else if (i < 393216) { src = w0; off = i - 262144; }
        else { src = w1; off = i - 393216; }
        f32x4 v = ldf4(src + off);
#pragma unroll
        for (int u = 0; u < 4; u++) out[i + u] = __float2bfloat16(v[u]);
        return;
    }
    // statsA for x: CH=256 fp32, P=128 blocks, RB=256 rows, SLOTS=4, ITER=64
    int bx = blockIdx.x - 512;
    int cv = tid & 63, slot = tid >> 6;
    int c0 = cv * 4;
    size_t row0 = (size_t)bx * 256 + slot;
    float s[4], s2[4];
#pragma unroll
    for (int u = 0; u < 4; u++) { s[u] = 0.f; s2[u] = 0.f; }
    for (int i = 0; i < 64; i++) {
        size_t row = row0 + (size_t)i * 4;
        f32x4 v = ldf4(X + row * 256 + c0);
#pragma unroll
        for (int u = 0; u < 4; u++) {
            float f = v[u];
            s[u] += f; s2[u] += f * f;
        }
    }
    __shared__ float red[256][8];
#pragma unroll
    for (int u = 0; u < 4; u++) {
        red[tid][u] = s[u];
        red[tid][4 + u] = s2[u];
    }
    __syncthreads();
    if (tid < 64) {
#pragma unroll
        for (int sl = 1; sl < 4; sl++)
#pragma unroll
            for (int u = 0; u < 4; u++) {
                s[u] += red[tid + sl * 64][u];
                s2[u] += red[tid + sl * 64][4 + u];
            }
        float* dst = part + (size_t)bx * 512;
#pragma unroll
        for (int u = 0; u < 4; u++) {
            dst[c0 + u] = s[u];
            dst[256 + c0 + u] = s2[u];
        }
    }
}

// ---------------- stats stage A (wide CH, bf16): disjoint channels, NO atomics ----------------
template <int CH, int P, int ROWS>
__global__ __launch_bounds__(256) void statsA_wide(const bf16* __restrict__ X,
                                                   float* __restrict__ part) {
    constexpr int RB = ROWS / P;
    int c0 = (blockIdx.x * 256 + threadIdx.x) * 8;
    size_t row0 = (size_t)blockIdx.y * RB;
    float s[8], s2[8];
#pragma unroll
    for (int u = 0; u < 8; u++) { s[u] = 0.f; s2[u] = 0.f; }
    for (int i = 0; i < RB; i++) {
        bf16x8 v = ld8(X + (row0 + i) * CH + c0);
#pragma unroll
        for (int u = 0; u < 8; u++) {
            float f = (float)v[u];
            s[u] += f; s2[u] += f * f;
        }
    }
    float* dst = part + (size_t)blockIdx.y * (2 * CH);
#pragma unroll
    for (int u = 0; u < 8; u++) {
        dst[c0 + u] = s[u];
        dst[CH + c0 + u] = s2[u];
    }
}

// ---------------- stage B: parallel reduce partials + finalize -> scale/bias ----------------
// grid = nch/64 blocks; 256 threads = 64 channels x 4 P-slices; coalesced loads.
// ps: post-scale folded into both scale and bias (e.g. 1/sqrt(C) for the energy BN)
__global__ __launch_bounds__(256) void statsB(const float* __restrict__ part, int P,
                                              int nch, float inv_n, float ps,
                                              const float* __restrict__ gamma,
                                              const float* __restrict__ beta,
                                              float* __restrict__ scale,
                                              float* __restrict__ bias) {
    int cl = threadIdx.x & 63, sl = threadIdx.x >> 6;
    int c = blockIdx.x * 64 + cl;
    float s = 0.f, s2 = 0.f;
    for (int p = sl; p < P; p += 4) {
        s += part[(size_t)p * 2 * nch + c];
        s2 += part[(size_t)p * 2 * nch + nch + c];
    }
    __shared__ float red[2][4][64];
    red[0][sl][cl] = s;
    red[1][sl][cl] = s2;
    __syncthreads();
    if (threadIdx.x < 64) {
        s = red[0][0][cl] + red[0][1][cl] + red[0][2][cl] + red[0][3][cl];
        s2 = red[1][0][cl] + red[1][1][cl] + red[1][2][cl] + red[1][3][cl];
        float mean = s * inv_n;
        float var = s2 * inv_n - mean * mean;
        float rstd = rsqrtf(var + BNEPS);
        float sc = gamma[c] * rstd;
        scale[c] = sc * ps;
        bias[c] = (beta[c] - mean * sc) * ps;
    }
}

// =====================================================================================
// LDS-staged 128x128 NT GEMM core: BK=64, 4 waves x (4x4 16x16x32 MFMA).
// LDS tiles As/Bs [128][64] are XOR-SWIZZLED (T2): 16B-group slot s of row r holds
// global group s ^ (r&7). Direct staging achieves this by pre-swizzling the GLOBAL
// source column (gload_lds writes linearly); reg-staged A swizzles the ds_write dest.
// Fragment reads use col ((g ^ (l16&7)) << 3) -> each 8-lane phase hits 8 distinct
// 16B slots = 32 banks (was: 16-way conflict on a 128B-stride row-major tile).
// B operand: always global_load_lds width-16 direct staging.
// A operand (ASRC): 0 = bf16 direct (gload_lds)
//                   1 = fp32 + fused BN affine           (replaces bn_apply_f32<false>)
//                   2 = fp32 + fused BN affine + ReLU    (replaces bn_apply_f32<true>)
//                   3 = bf16 + fused BN affine + ReLU    (replaces bn_apply_bf16<true>)
// MODE 0: C -> bf16; MODE 1: C + bias + resf -> fp32; MODE 2: C + resf -> fp32
// STATS: fuse BN stage-A partial sum/sumsq of output -> spart[m-block][2*N]
// =====================================================================================
template <int MODE, bool STATS, int ASRC>
__device__ __forceinline__ void gemm_core(
    const bf16* __restrict__ A, const float* __restrict__ Af,
    const bf16* __restrict__ B, int m0, int n0, int N, int K,
    const float* __restrict__ a_scale, const float* __restrict__ a_bias,
    const float* __restrict__ bias, const float* __restrict__ resf,
    bf16* __restrict__ outb, float* __restrict__ outf, float* __restrict__ spart,
    char* smem) {
    bf16* As = (bf16*)smem;        // [128][64] swizzled
    bf16* Bs = As + 128 * 64;      // [128][64] swizzled
    int tid = threadIdx.x;
    int lane = tid & 63, wave = tid >> 6;
    int quad = lane >> 4, l16 = lane & 15;
    int wm = (wave >> 1) * 64, wn = (wave & 1) * 64;
    int srow = lane >> 3;          // 0..7   staging row within 8-row group
    int scol = (lane & 7) * 8;     // 0..56  linear staging col (elements)
    int sgc = (((lane & 7) ^ srow) << 3);  // swizzled 16B-group col (elements)
    const bf16* Ab = (ASRC == 0) ? A + (size_t)m0 * K : A;
    const bf16* Bb = B + (size_t)n0 * K;
    f32x4 acc[4][4];
#pragma unroll
    for (int i = 0; i < 4; i++)
#pragma unroll
        for (int j = 0; j < 4; j++) acc[i][j] = f32x4{0.f, 0.f, 0.f, 0.f};

    for (int kt = 0; kt < K; kt += 64) {
        if (kt) __syncthreads();  // prior compute done before LDS overwrite
        // B: async direct staging, pre-swizzled global source col
#pragma unroll
        for (int i = 0; i < 4; i++) {
            int r = i * 32 + wave * 8;  // wave-uniform LDS base row
            gload_lds16(Bb + (size_t)(r + srow) * K + kt + sgc, Bs + r * 64);
        }
        if (ASRC == 0) {
#pragma unroll
            for (int i = 0; i < 4; i++) {
                int r = i * 32 + wave * 8;
                gload_lds16(Ab + (size_t)(r + srow) * K + kt + sgc, As + r * 64);
            }
        } else {
            int c = kt + scol;
            f32x4 s0 = ldf4(a_scale + c), s1 = ldf4(a_scale + c + 4);
            f32x4 b0 = ldf4(a_bias + c), b1 = ldf4(a_bias + c + 4);
#pragma unroll
            for (int i = 0; i < 4; i++) {
                int r = i * 32 + wave * 8;
                size_t row = (size_t)(m0 + r + srow);
                bf16x8 av;
                if (ASRC == 3) {
                    bf16x8 xv = ld8(Ab + row * K + c);
#pragma unroll
                    for (int u = 0; u < 4; u++) {
                        float f = (float)xv[u] * s0[u] + b0[u];
                        f = fmaxf(f, 0.f);
                        av[u] = (__bf16)__float2bfloat16(f);
                    }
#pragma unroll
                    for (int u = 0; u < 4; u++) {
                        float f = (float)xv[u + 4] * s1[u] + b1[u];
                        f = fmaxf(f, 0.f);
                        av[u + 4] = (__bf16)__float2bfloat16(f);
                    }
                } else {
                    f32x4 x0 = ldf4(Af + row * K + c), x1v = ldf4(Af + row * K + c + 4);
#pragma unroll
                    for (int u = 0; u < 4; u++) {
                        float f = x0[u] * s0[u] + b0[u];
                        if (ASRC == 2) f = fmaxf(f, 0.f);
                        av[u] = (__bf16)__float2bfloat16(f);
                    }
#pragma unroll
                    for (int u = 0; u < 4; u++) {
                        float f = x1v[u] * s1[u] + b1[u];
                        if (ASRC == 2) f = fmaxf(f, 0.f);
                        av[u + 4] = (__bf16)__float2bfloat16(f);
                    }
                }
                st8(As + (r + srow) * 64 + sgc, av);  // swizzled dest slot
            }
        }
        __syncthreads();  // drains vmcnt + lgkm -> staged data visible
#pragma unroll
        for (int ks = 0; ks < 2; ks++) {
#pragma unroll
            for (int uu = 0; uu < 1; uu++) {}  // (keep structure flat)
            bf16x8 af[4], bfr[4];
            int gq = ks * 4 + quad;                 // global 16B-group 0..7
            int kb_ = ((gq ^ (l16 & 7)) << 3);      // swizzled read col
#pragma unroll
            for (int i = 0; i < 4; i++)
                af[i] = ld8(As + (wm + i * 16 + l16) * 64 + kb_);
#pragma unroll
            for (int j = 0; j < 4; j++)
                bfr[j] = ld8(Bs + (wn + j * 16 + l16) * 64 + kb_);
#pragma unroll
            for (int i = 0; i < 4; i++)
#pragma unroll
                for (int j = 0; j < 4; j++)
                    acc[i][j] = __builtin_amdgcn_mfma_f32_16x16x32_bf16(
                        af[i], bfr[j], acc[i][j], 0, 0, 0);
        }
    }
    __syncthreads();  // all LDS reads done before epilogue reuse

    if (MODE == 0) {
        bf16(*Ct)[136] = (bf16(*)[136])smem;  // 128*136*2 = 34816 B
#pragma unroll
        for (int i = 0; i < 4; i++)
#pragma unroll
            for (int j = 0; j < 4; j++)
#pragma unroll
                for (int r = 0; r < 4; r++)
                    Ct[wm + i * 16 + quad * 4 + r][wn + j * 16 + l16] =
                        __float2bfloat16(acc[i][j][r]);
        __syncthreads();
        float s[8], s2[8];
        if (STATS) {
#pragma unroll
            for (int u = 0; u < 8; u++) { s[u] = 0.f; s2[u] = 0.f; }
        }
#pragma unroll
        for (int it = 0; it < 8; it++) {
            int idx = it * 256 + tid;
            int row = idx >> 4, colv = idx & 15;  // colv == tid & 15 (constant)
            bf16x8 c = ld8(&Ct[row][colv * 8]);
            st8(outb + (size_t)(m0 + row) * N + n0 + colv * 8, c);
            if (STATS) {
#pragma unroll
                for (int u = 0; u < 8; u++) {
                    float f = (float)c[u];
                    s[u] += f; s2[u] += f * f;
                }
            }
        }
        if (STATS) {
            __syncthreads();
            float* rf = (float*)smem;  // 256*16*4 = 16 KB
            int g = tid & 15, k = tid >> 4;
#pragma unroll
            for (int u = 0; u < 8; u++) {
                rf[(g * 16 + k) * 16 + u] = s[u];
                rf[(g * 16 + k) * 16 + 8 + u] = s2[u];
            }
            __syncthreads();
            if (tid < 16) {
                float a[8], b[8];
#pragma unroll
                for (int u = 0; u < 8; u++) { a[u] = 0.f; b[u] = 0.f; }
                for (int k2 = 0; k2 < 16; k2++)
#pragma unroll
                    for (int u = 0; u < 8; u++) {
                        a[u] += rf[(tid * 16 + k2) * 16 + u];
                        b[u] += rf[(tid * 16 + k2) * 16 + 8 + u];
                    }
                float* dst = spart + (size_t)(m0 >> 7) * 2 * N + n0 + tid * 8;
#pragma unroll
                for (int u = 0; u < 8; u++) {
                    dst[u] = a[u];
                    dst[N + u] = b[u];
                }
            }
        }
    } else {
        float(*Cf)[132] = (float(*)[132])smem;  // 64*132*4 = 33792 B
        float s[4], s2[4];
        if (STATS) {
#pragma unroll
            for (int u = 0; u < 4; u++) { s[u] = 0.f; s2[u] = 0.f; }
        }
#pragma unroll
        for (int h = 0; h < 2; h++) {
            if (h) __syncthreads();
            if ((wm >> 6) == h) {  // waves owning rows [h*64, h*64+64)
#pragma unroll
                for (int i = 0; i < 4; i++)
#pragma unroll
                    for (int j = 0; j < 4; j++)
#pragma unroll
                        for (int r = 0; r < 4; r++)
                            Cf[i * 16 + quad * 4 + r][wn + j * 16 + l16] = acc[i][j][r];
            }
            __syncthreads();
#pragma unroll
            for (int it = 0; it < 8; it++) {
                int idx = it * 256 + tid;
                int row = idx >> 5, cv = (idx & 31) * 4;  // cv == (tid&31)*4 (constant)
                f32x4 v = ldf4(&Cf[row][cv]);
                int gc = n0 + cv;
                size_t gi = (size_t)(m0 + h * 64 + row) * N + gc;
                f32x4 rr = ldf4(resf + gi);
                if (MODE == 1) {
                    f32x4 bb = ldf4(bias + gc);
                    v = v + bb + rr;
                } else {
                    v = v + rr;
                }
                *reinterpret_cast<f32x4*>(outf + gi) = v;
                if (STATS) {
#pragma unroll
                    for (int u = 0; u < 4; u++) {
                        s[u] += v[u]; s2[u] += v[u] * v[u];
                    }
                }
            }
        }
        if (STATS) {
            __syncthreads();
            float* rf = (float*)smem;  // 256*8*4 = 8 KB
            int g = tid & 31, k = tid >> 5;
#pragma unroll
            for (int u = 0; u < 4; u++) {
                rf[(g * 8 + k) * 8 + u] = s[u];
                rf[(g * 8 + k) * 8 + 4 + u] = s2[u];
            }
            __syncthreads();
            if (tid < 32) {
                float a[4], b[4];
#pragma unroll
                for (int u = 0; u < 4; u++) { a[u] = 0.f; b[u] = 0.f; }
                for (int k2 = 0; k2 < 8; k2++)
#pragma unroll
                    for (int u = 0; u < 4; u++) {
                        a[u] += rf[(tid * 8 + k2) * 8 + u];
                        b[u] += rf[(tid * 8 + k2) * 8 + 4 + u];
                    }
                float* dst = spart + (size_t)(m0 >> 7) * 2 * N + n0 + tid * 4;
#pragma unroll
                for (int u = 0; u < 4; u++) {
                    dst[u] = a[u];
                    dst[N + u] = b[u];
                }
            }
        }
    }
}

template <int MODE, bool STATS, int ASRC>
__global__ __launch_bounds__(256) void gemm128(
    const bf16* __restrict__ A, const float* __restrict__ Af,
    const bf16* __restrict__ B, int N, int K, const float* __restrict__ a_scale,
    const float* __restrict__ a_bias, const float* __restrict__ bias,
    const float* __restrict__ resf, bf16* __restrict__ outb,
    float* __restrict__ outf, float* __restrict__ spart) {
    __shared__ __align__(16) char smem[34816];
    gemm_core<MODE, STATS, ASRC>(A, Af, B, blockIdx.x * 128, blockIdx.y * 128, N, K,
                                 a_scale, a_bias, bias, resf, outb, outf, spart, smem);
}

// QKV fused: A = BN(x) computed in staging from fp32 x + bn1 scale/bias.
// Wq|Wk|Wv contiguous at WB, q|k|v buffers contiguous at qb. grid (256, 6).
__global__ __launch_bounds__(256) void gemm_qkv128(const float* __restrict__ x,
                                                   const bf16* __restrict__ W,
                                                   const float* __restrict__ a_scale,
                                                   const float* __restrict__ a_bias,
                                                   bf16* __restrict__ qkv) {
    __shared__ __align__(16) char smem[34816];
    int mat = blockIdx.y >> 1;
    int n0 = (blockIdx.y & 1) * 128;
    gemm_core<0, false, 1>(nullptr, x, W + mat * 65536, blockIdx.x * 128, n0, CC, CC,
                           a_scale, a_bias, nullptr, nullptr,
                           qkv + (size_t)mat * 8388608, nullptr, nullptr, smem);
}

// ---------------- energy = Q K^T per (n,h): one block per nh, 128x128 tile ----------------
__global__ __launch_bounds__(256) void gemm_energy(const bf16* __restrict__ q,
                                                   const bf16* __restrict__ k,
                                                   bf16* __restrict__ E) {
    int nh = blockIdx.x;
    int nb = nh >> 3, hh = nh & 7;
    int tid = threadIdx.x;
    int lane = tid & 63, wave = tid >> 6;
    int quad = lane >> 4, l16 = lane & 15;
    int wm = (wave >> 1) * 64, wn = (wave & 1) * 64;
    size_t tb = (size_t)nb * SS;
    int cb = hh * DD + quad * 8;
    f32x4 zero = {0.f, 0.f, 0.f, 0.f};
    f32x4 acc[4][4];
#pragma unroll
    for (int i = 0; i < 4; i++)
#pragma unroll
        for (int j = 0; j < 4; j++) acc[i][j] = zero;
    bf16x8 af[4], bfg[4];
#pragma unroll
    for (int i = 0; i < 4; i++)
        af[i] = ld8(q + (tb + wm + i * 16 + l16) * CC + cb);
#pragma unroll
    for (int j = 0; j < 4; j++)
        bfg[j] = ld8(k + (tb + wn + j * 16 + l16) * CC + cb);
#pragma unroll
    for (int i = 0; i < 4; i++)
#pragma unroll
        for (int j = 0; j < 4; j++)
            acc[i][j] = __builtin_amdgcn_mfma_f32_16x16x32_bf16(af[i], bfg[j], acc[i][j], 0, 0, 0);
    __shared__ bf16 Et[128][136];
#pragma unroll
    for (int i = 0; i < 4; i++)
#pragma unroll
        for (int j = 0; j < 4; j++)
#pragma unroll
            for (int r = 0; r < 4; r++)
                Et[wm + i * 16 + quad * 4 + r][wn + j * 16 + l16] =
                    __float2bfloat16(acc[i][j][r]);
    __syncthreads();
    bf16* Eb = E + (size_t)nh * SS * SS;
#pragma unroll
    for (int it = 0; it < 8; it++) {
        int idx = it * 256 + tid;
        int row = idx >> 4, colv = idx & 15;
        st8(Eb + (size_t)row * SS + colv * 8, ld8(&Et[row][colv * 8]));
    }
}

// ---------------- BN(energy) + softmax + P V^T per (n,h) ----------------
// P,Vt XOR-swizzled (no padding): LDS = 40960 B -> exactly 4 blocks/CU.
// BN-affine (0.0625 pre-folded in statsB) + softmax fused in registers.
__global__ __launch_bounds__(256, 4) void att_kernel(
    const bf16* __restrict__ E, const bf16* __restrict__ v,
    const float* __restrict__ pe_scale, const float* __restrict__ pe_bias,
    bf16* __restrict__ o) {
    __shared__ bf16 P[SS * 128];   // swizzled [128][128]
    __shared__ bf16 Vt[DD * 128];  // swizzled [32][128]
    int nh = blockIdx.x;
    int nb = nh >> 3, hh = nh & 7;
    const bf16* Eb = E + (size_t)nh * SS * SS;
    int tid = threadIdx.x;
    int wave = tid >> 6, lane = tid & 63;
    // phase 0: transpose token-major v tile into Vt[d][s] (swizzled)
    {
        int s = tid >> 1, d0 = (tid & 1) * 16;
        const bf16* vp = v + (size_t)(nb * SS + s) * CC + hh * DD + d0;
        bf16x8 v0 = ld8(vp), v1 = ld8(vp + 8);
        int g = s >> 3, sub = s & 7;
#pragma unroll
        for (int u = 0; u < 8; u++) {
            int da = d0 + u, db = d0 + 8 + u;
            Vt[da * 128 + swzg(da, g) + sub] = bfc(v0[u]);
            Vt[db * 128 + swzg(db, g) + sub] = bfc(v1[u]);
        }
    }
    // phase A: fused BN + softmax; wave owns rows [wave*32, wave*32+32)
    int rs = lane >> 4, cg = lane & 15;
#pragma unroll
    for (int p = 0; p < 8; p++) {
        int r = wave * 32 + p * 4 + rs;
        int e8 = r * 128 + cg * 8;
        bf16x8 ev = ld8(Eb + e8);
        f32x4 s0 = ldf4(pe_scale + e8), s1 = ldf4(pe_scale + e8 + 4);
        f32x4 b0 = ldf4(pe_bias + e8), b1 = ldf4(pe_bias + e8 + 4);
        float l[8];
#pragma unroll
        for (int u = 0; u < 4; u++) l[u] = (float)ev[u] * s0[u] + b0[u];
#pragma unroll
        for (int u = 0; u < 4; u++) l[u + 4] = (float)ev[u + 4] * s1[u] + b1[u];
        float mx = fmaxf(fmaxf(fmaxf(l[0], l[1]), fmaxf(l[2], l[3])),
                         fmaxf(fmaxf(l[4], l[5]), fmaxf(l[6], l[7])));
#pragma unroll
        for (int off = 8; off; off >>= 1) mx = fmaxf(mx, __shfl_xor(mx, off, 16));
        float e[8], sm = 0.f;
#pragma unroll
        for (int u = 0; u < 8; u++) { e[u] = __expf(l[u] - mx); sm += e[u]; }
#pragma unroll
        for (int off = 8; off; off >>= 1) sm += __shfl_xor(sm, off, 16);
        float inv = 1.0f / sm;
        bf16x8 pv;
#pragma unroll
        for (int u = 0; u < 8; u++) pv[u] = (__bf16)__float2bfloat16(e[u] * inv);
        st8(&P[r * 128 + swzg(r, cg)], pv);
    }
    __syncthreads();  // Vt (cross-thread) visible; P rows are own-wave only
    // phase 3: O = P @ V^T
    int quad = lane >> 4, l16 = lane & 15;
    f32x4 acc[2][2];
#pragma unroll
    for (int i = 0; i < 2; i++)
#pragma unroll
        for (int j = 0; j < 2; j++) acc[i][j] = f32x4{0.f, 0.f, 0.f, 0.f};
#pragma unroll
    for (int kk = 0; kk < SS; kk += 32) {
        int g = (kk >> 3) + quad;  // 16B-group index 0..15
        int r0 = wave * 32 + l16, r1 = r0 + 16;
        bf16x8 a0 = ld8(&P[r0 * 128 + swzg(r0, g)]);
        bf16x8 a1 = ld8(&P[r1 * 128 + swzg(r1, g)]);
        bf16x8 b0 = ld8(&Vt[l16 * 128 + swzg(l16, g)]);
        bf16x8 b1 = ld8(&Vt[(l16 + 16) * 128 + swzg(l16 + 16, g)]);
        acc[0][0] = __builtin_amdgcn_mfma_f32_16x16x32_bf16(a0, b0, acc[0][0], 0, 0, 0);
        acc[0][1] = __builtin_amdgcn_mfma_f32_16x16x32_bf16(a0, b1, acc[0][1], 0, 0, 0);
        acc[1][0] = __builtin_amdgcn_mfma_f32_16x16x32_bf16(a1, b0, acc[1][0], 0, 0, 0);
        acc[1][1] = __builtin_amdgcn_mfma_f32_16x16x32_bf16(a1, b1, acc[1][1], 0, 0, 0);
    }
    __syncthreads();  // all waves done reading P before reuse as O tile
    bf16* Ob = P;     // reuse as [128][40]
#pragma unroll
    for (int i = 0; i < 2; i++)
#pragma unroll
        for (int j = 0; j < 2; j++)
#pragma unroll
            for (int r = 0; r < 4; r++) {
                int row = wave * 32 + i * 16 + quad * 4 + r;
                int col = j * 16 + l16;
                Ob[row * 40 + col] = __float2bfloat16(acc[i][j][r]);
            }
    __syncthreads();
#pragma unroll
    for (int it = 0; it < 2; it++) {
        int idx = it * 256 + tid;
        int row = idx >> 2, colv = idx & 3;
        st8(o + (size_t)(nb * SS + row) * CC + hh * DD + colv * 8,
            ld8(&Ob[row * 40 + colv * 8]));
    }
}

// ---------------- workspace layout (bytes) ----------------
#define WB_OFF 0u
#define O_OFF 1048576u      /* obuf bf16 16.7MB */
#define Q_OFF 17825792u
#define K_OFF 34603008u
#define VT_OFF 51380224u
#define E_OFF 68157440u
#define X1_OFF 17825792u    /* fp32, over q+k */
#define OUT2_OFF 68157440u  /* over E 1st half (E dead after att) */
/* transient scale/bias + partial homes (dead windows):
   bn1 s/b  -> E_OFF (2 KB);      x  partial -> E_OFF+64K (256 KB)  [E dead until energy]
   pe  s/b  -> Q_OFF (128 KB);    pe partial -> Q_OFF+128K (4 MB)   [q dead after energy]
   x1 partial -> VT_OFF (512 KB)  [vb dead after att]
   bn0 s/b  -> O_OFF (2 KB)       [obuf dead after Wo gemm]
   f1  s/b  -> O_OFF+4K (4 KB);   f1 partial -> O_OFF+16K (1 MB) */

extern "C" void kernel_launch(void* const* d_in, const int* in_sizes, int n_in,
                              void* d_out, int out_size, void* d_ws, size_t ws_size,
                              hipStream_t stream) {
    const float* x = (const float*)d_in[0];
    const float* g_n = (const float*)d_in[1];
    const float* b_n = (const float*)d_in[2];
    const float* Wq = (const float*)d_in[3];
    const float* Wk = (const float*)d_in[4];
    const float* Wv = (const float*)d_in[5];
    const float* Wo = (const float*)d_in[6];
    const float* bo = (const float*)d_in[7];
    const float* g_pe = (const float*)d_in[8];
    const float* b_pe = (const float*)d_in[9];
    const float* g0 = (const float*)d_in[10];
    const float* b0 = (const float*)d_in[11];
    const float* W0 = (const float*)d_in[12];
    const float* g1 = (const float*)d_in[13];
    const float* b1 = (const float*)d_in[14];
    const float* W1 = (const float*)d_in[15];

    char* ws = (char*)d_ws;
    bf16* WB = (bf16*)(ws + WB_OFF);
    bf16* WOB = WB + 196608;
    bf16* W0B = WB + 262144;
    bf16* W1B = WB + 393216;
    bf16* qb = (bf16*)(ws + Q_OFF);
    bf16* kb = (bf16*)(ws + K_OFF);
    bf16* vb = (bf16*)(ws + VT_OFF);
    bf16* Ebuf = (bf16*)(ws + E_OFF);
    bf16* obuf = (bf16*)(ws + O_OFF);
    float* x1 = (float*)(ws + X1_OFF);
    bf16* out2 = (bf16*)(ws + OUT2_OFF);
    float* bn1_scale = (float*)(ws + E_OFF);
    float* bn1_bias = bn1_scale + 256;
    float* xpart = (float*)(ws + E_OFF + 65536);
    float* pe_scale = (float*)(ws + Q_OFF);
    float* pe_bias = pe_scale + 16384;
    float* pepart = (float*)(ws + Q_OFF + 131072);
    float* bn0_scale = (float*)(ws + O_OFF);
    float* bn0_bias = bn0_scale + 256;
    float* f1_scale = (float*)(ws + O_OFF + 4096);
    float* f1_bias = f1_scale + 512;
    float* x1part = (float*)(ws + VT_OFF);          // 512 KB, vb dead window
    float* f1part = (float*)(ws + O_OFF + 16384);   // 1 MB, obuf dead
    float* outp = (float*)d_out;

    // weights fp32 -> bf16  ∥  statsA(x)
    prep<<<640, 256, 0, stream>>>(Wq, Wk, Wv, Wo, W0, W1, WB, x, xpart);
    statsB<<<4, 256, 0, stream>>>(xpart, 128, 256, 1.0f / 32768.0f, 1.0f, g_n, b_n,
                                  bn1_scale, bn1_bias);
    // QKV with fused BN(x) in A-staging (token-major outputs)
    gemm_qkv128<<<dim3(256, 6), 256, 0, stream>>>(x, WB, bn1_scale, bn1_bias, qb);
    // energy: one block per (n,h)
    gemm_energy<<<NHB, 256, 0, stream>>>(qb, kb, Ebuf);
    // --- BN(energy), 1/sqrt(C) folded into scale/bias ---
    statsA_wide<16384, 32, 2048><<<dim3(8, 32), 256, 0, stream>>>(Ebuf, pepart);
    statsB<<<256, 256, 0, stream>>>(pepart, 32, 16384, 1.0f / 2048.0f, 0.0625f, g_pe,
                                    b_pe, pe_scale, pe_bias);
    // BN + softmax + PV
    att_kernel<<<NHB, 256, 0, stream>>>(Ebuf, vb, pe_scale, pe_bias, obuf);
    // x1 = o @ Wo^T + bo + x (fp32), fused statsA(x1) -> x1part
    gemm128<1, true, 0><<<dim3(256, 2), 256, 0, stream>>>(
        obuf, nullptr, WOB, CC, CC, nullptr, nullptr, bo, x, nullptr, x1, x1part);
    statsB<<<4, 256, 0, stream>>>(x1part, 256, 256, 1.0f / 32768.0f, 1.0f, g0, b0,
                                  bn0_scale, bn0_bias);
    // out2 = relu(BN(x1)) @ W0^T (BN fused in A-staging), fused statsA(out2) -> f1part
    gemm128<0, true, 2><<<dim3(256, 4), 256, 0, stream>>>(
        nullptr, x1, W0B, 2 * CC, CC, bn0_scale, bn0_bias, nullptr, nullptr, out2,
        nullptr, f1part);
    statsB<<<8, 256, 0, stream>>>(f1part, 256, 512, 1.0f / 32768.0f, 1.0f, g1, b1,
                                  f1_scale, f1_bias);
    // out = relu(BN(out2)) @ W1^T + x1 (BN fused in A-staging), fp32 out
    gemm128<2, false, 3><<<dim3(256, 2), 256, 0, stream>>>(
        out2, nullptr, W1B, CC, 2 * CC, f1_scale, f1_bias, nullptr, x1, nullptr, outp,
        nullptr);
    (void)in_sizes; (void)n_in; (void)out_size; (void)ws_size;
    (void)kb; (void)vb;
}